// Round 1
// baseline (12448.389 us; speedup 1.0000x reference)
//
#include <hip/hip_runtime.h>
#include <math.h>

// ---------------- problem constants ----------------
#define ATOT 261888          // sum over levels of H*W*3
#define MCAND 21840          // 6000+6000+6000+3072+768 candidates per image
#define POSTK 1000
#define CMB (2*ATOT*5)       // combined output floats = 2618880
#define KB_OFF CMB           // keep_boxes offset in d_out
#define KS_OFF (CMB+8000)    // keep_scores
#define KV_OFF (CMB+10000)   // valid
#define SCALE_CLAMP 4.135166556742356f

// ---------------- ws layout (float units) ----------------
#define WS_T   0
#define WS_SC  (256*65536)            // 16777216  (t buffer: one image, largest level)
#define WS_CB  (WS_SC + 2*ATOT)       // scores: 2*261888
#define WS_CS  (WS_CB + 2*MCAND*4)    // cand boxes
#define WS_CTL (WS_CS + 2*MCAND)      // cand scores -> then ctl (u32)

// ctl indices (u32)
#define C_PRE 0
#define C_KCUR 6
#define C_CNT 12
#define C_TIE 18
#define C_GH 32
#define C_TIEIDX (C_GH + 6*256)
#define CTL_SIZE (C_TIEIDX + 6*1024)

__device__ const int LW[5]    = {256,128,64,32,16};
__device__ const int LM[5]    = {196608,49152,12288,3072,768};
__device__ const int LBASE[5] = {0,196608,245760,258048,261120};
__device__ const int LSTR[5]  = {4,8,16,32,64};
__device__ const int LSZ[5]   = {32,64,128,256,512};
__device__ const int CBASE[5] = {0,6000,12000,18000,21072};

__device__ inline unsigned fkey(float f) {
  unsigned u = __float_as_uint(f);
  return u ^ (unsigned)(((int)u >> 31) | 0x80000000);
}
__device__ inline float unfkey(unsigned k) {
  unsigned u = (k & 0x80000000u) ? (k ^ 0x80000000u) : ~k;
  return __uint_as_float(u);
}

// ---------------- conv3x3 + bias + relu ----------------
// block 256, tile: 64 out-ch x (4h x 16w). grid (W/16, H/4, 4). single image.
#define CHK 8
__global__ __launch_bounds__(256) void conv3x3_relu(
    const float* __restrict__ in, const float* __restrict__ wgt,
    const float* __restrict__ bias, float* __restrict__ outp, int H, int W) {
  const int tid = threadIdx.x;
  const int x0 = blockIdx.x * 16;
  const int y0 = blockIdx.y * 4;
  const int koB = blockIdx.z * 64;
  __shared__ float inS[CHK][6][18];
  __shared__ float wS[CHK*9*64];
  const int HW = H * W;
  const int tko = (tid >> 4) << 2;        // 0..60 step4
  const int px = (tid & 3) << 2;          // 0,4,8,12
  const int py = (tid >> 2) & 3;          // 0..3
  float acc[4][4] = {};
  for (int c0 = 0; c0 < 256; c0 += CHK) {
    for (int i = tid; i < CHK*6*18; i += 256) {
      int ci = i / 108; int r = i % 108; int iy = r / 18; int ix = r % 18;
      int gy = y0 + iy - 1, gx = x0 + ix - 1;
      float v = 0.f;
      if (gy >= 0 && gy < H && gx >= 0 && gx < W) v = in[(c0+ci)*HW + gy*W + gx];
      inS[ci][iy][ix] = v;
    }
    // weights: coalesced global (ci,kk contiguous runs), rotated LDS store (conflict-free)
    for (int i = tid; i < CHK*9*64; i += 256) {
      int ko = i / 72; int r = i % 72;    // r = ci*9 + kk
      float v = wgt[((koB+ko)*256 + c0 + (r/9))*9 + (r%9)];
      wS[r*64 + ((ko + r) & 63)] = v;
    }
    __syncthreads();
    #pragma unroll
    for (int ci = 0; ci < CHK; ++ci) {
      #pragma unroll
      for (int kh = 0; kh < 3; ++kh) {
        float iv[6];
        #pragma unroll
        for (int j = 0; j < 6; ++j) iv[j] = inS[ci][py+kh][px+j];
        #pragma unroll
        for (int kw = 0; kw < 3; ++kw) {
          int r = ci*9 + kh*3 + kw;
          float w0 = wS[r*64 + ((tko+0+r)&63)];
          float w1 = wS[r*64 + ((tko+1+r)&63)];
          float w2 = wS[r*64 + ((tko+2+r)&63)];
          float w3 = wS[r*64 + ((tko+3+r)&63)];
          #pragma unroll
          for (int j = 0; j < 4; ++j) {
            float x = iv[kw+j];
            acc[0][j] += w0*x; acc[1][j] += w1*x;
            acc[2][j] += w2*x; acc[3][j] += w3*x;
          }
        }
      }
    }
    __syncthreads();
  }
  const int oy = y0 + py, ox = x0 + px;
  #pragma unroll
  for (int k = 0; k < 4; ++k) {
    float bb = bias[koB + tko + k];
    float4 v;
    v.x = fmaxf(acc[k][0] + bb, 0.f);
    v.y = fmaxf(acc[k][1] + bb, 0.f);
    v.z = fmaxf(acc[k][2] + bb, 0.f);
    v.w = fmaxf(acc[k][3] + bb, 0.f);
    *(float4*)&outp[(koB+tko+k)*HW + oy*W + ox] = v;
  }
}

// ---------------- 1x1 heads: writes combined + scores ----------------
__global__ __launch_bounds__(256) void heads1x1(
    const float* __restrict__ t, const float* __restrict__ ow, const float* __restrict__ ob,
    const float* __restrict__ dw, const float* __restrict__ db,
    float* __restrict__ comb, float* __restrict__ scores, int HW, int lbase, int n) {
  __shared__ float wS[15][256];
  const int tid = threadIdx.x;
  for (int i = tid; i < 3*256; i += 256) wS[i>>8][i&255] = ow[i];
  for (int i = tid; i < 12*256; i += 256) wS[3+(i>>8)][i&255] = dw[i];
  __syncthreads();
  int p0 = (blockIdx.x*256 + tid) * 4;
  if (p0 >= HW) return;
  float acc[15][4] = {};
  for (int c = 0; c < 256; ++c) {
    float4 v = *(const float4*)&t[c*HW + p0];
    float vv[4] = {v.x, v.y, v.z, v.w};
    #pragma unroll
    for (int k = 0; k < 15; ++k) {
      float w = wS[k][c];
      #pragma unroll
      for (int j = 0; j < 4; ++j) acc[k][j] += w * vv[j];
    }
  }
  float obv[3]; for (int i2 = 0; i2 < 3; ++i2) obv[i2] = ob[i2];
  float dbv[12]; for (int i2 = 0; i2 < 12; ++i2) dbv[i2] = db[i2];
  for (int j = 0; j < 4; ++j) {
    int pos = p0 + j;
    long base = (long)n*ATOT + lbase + (long)pos*3;
    #pragma unroll
    for (int a = 0; a < 3; ++a) {
      float lg = acc[a][j] + obv[a];
      comb[(base+a)*5] = lg;
      scores[(long)n*ATOT + lbase + pos*3 + a] = lg;
      #pragma unroll
      for (int q = 0; q < 4; ++q)
        comb[(base+a)*5 + 1 + q] = acc[3 + a*4 + q][j] + dbv[a*4+q];
    }
  }
}

// ---------------- decode (matches reference fp32 ops; anchors in f64 then cast) ----
__device__ void decode_store(int n, int lvl, int idx, int slot,
                             const float* comb, float* cboxes, float* cscores) {
  int W = LW[lvl];
  int a = idx % 3; int p = idx / 3;
  int wx = p % W, hy = p / W;
  double r = (a == 0) ? 0.5 : (a == 1) ? 1.0 : 2.0;
  double sz = (double)LSZ[lvl];
  double wsd = sqrt(sz*sz/r);
  double hsd = wsd * r;
  double cxd = (double)(wx * LSTR[lvl]);
  double cyd = (double)(hy * LSTR[lvl]);
  float ax1 = (float)(cxd - 0.5*wsd), ay1 = (float)(cyd - 0.5*hsd);
  float ax2 = (float)(cxd + 0.5*wsd), ay2 = (float)(cyd + 0.5*hsd);
  float aw = ax2 - ax1, ah = ay2 - ay1;
  float acx = ax1 + 0.5f*aw, acy = ay1 + 0.5f*ah;   // 0.5*aw exact
  long g = (long)n*ATOT + LBASE[lvl] + idx;
  const float* cm = comb + g*5;
  float sc = cm[0];
  float dx = cm[1], dy = cm[2], dwv = cm[3], dhv = cm[4];
  dwv = fminf(dwv, SCALE_CLAMP); dhv = fminf(dhv, SCALE_CLAMP);
  float pcx = __fadd_rn(__fmul_rn(dx, aw), acx);    // no fma contraction
  float pcy = __fadd_rn(__fmul_rn(dy, ah), acy);
  float pw = __fmul_rn(expf(dwv), aw);
  float ph = __fmul_rn(expf(dhv), ah);
  float x1 = __fsub_rn(pcx, 0.5f*pw), y1 = __fsub_rn(pcy, 0.5f*ph);
  float x2 = __fadd_rn(pcx, 0.5f*pw), y2 = __fadd_rn(pcy, 0.5f*ph);
  x1 = fminf(fmaxf(x1, 0.f), 1024.f);
  y1 = fminf(fmaxf(y1, 0.f), 1024.f);
  x2 = fminf(fmaxf(x2, 0.f), 1024.f);
  y2 = fminf(fmaxf(y2, 0.f), 1024.f);
  float* cbp = cboxes + ((long)n*MCAND + slot)*4;
  cbp[0]=x1; cbp[1]=y1; cbp[2]=x2; cbp[3]=y2;
  cscores[(long)n*MCAND + slot] = sc;
}

// ---------------- radix top-k (k=6000) for levels 0..2 x 2 images ----------------
__global__ void init_ctl(unsigned* ctl) {
  for (int i = threadIdx.x; i < CTL_SIZE; i += 256) ctl[i] = 0;
  __syncthreads();
  if (threadIdx.x < 6) ctl[C_KCUR + threadIdx.x] = 6000;
}

__global__ __launch_bounds__(256) void tk_hist(const float* __restrict__ scores,
                                               unsigned* ctl, int pass) {
  int t = blockIdx.y; int lvl = t >> 1, n = t & 1;
  int M = LM[lvl]; long base = (long)n*ATOT + LBASE[lvl];
  __shared__ unsigned h[256];
  h[threadIdx.x] = 0;
  __syncthreads();
  unsigned prefix = ctl[C_PRE + t];
  int shift = 24 - 8*pass;
  for (int i = blockIdx.x*256 + threadIdx.x; i < M; i += gridDim.x*256) {
    unsigned key = fkey(scores[base + i]);
    if (pass == 0 || (key >> (shift+8)) == prefix)
      atomicAdd(&h[(key >> shift) & 255], 1u);
  }
  __syncthreads();
  if (h[threadIdx.x]) atomicAdd(&ctl[C_GH + t*256 + threadIdx.x], h[threadIdx.x]);
}

__global__ __launch_bounds__(256) void tk_pick(unsigned* ctl) {
  int t = blockIdx.x;
  if (threadIdx.x == 0) {
    unsigned kcur = ctl[C_KCUR + t];
    int digit = 0;
    for (int d = 255; d >= 0; --d) {
      unsigned c = ctl[C_GH + t*256 + d];
      if (kcur <= c) { digit = d; break; }
      kcur -= c;
    }
    ctl[C_KCUR + t] = kcur;
    ctl[C_PRE + t] = (ctl[C_PRE + t] << 8) | (unsigned)digit;
  }
  __syncthreads();
  ctl[C_GH + t*256 + threadIdx.x] = 0;
}

__global__ __launch_bounds__(256) void tk_compact(const float* __restrict__ scores,
    const float* __restrict__ comb, unsigned* ctl, float* cboxes, float* cscores) {
  int t = blockIdx.y; int lvl = t >> 1, n = t & 1;
  int M = LM[lvl]; long base = (long)n*ATOT + LBASE[lvl];
  unsigned thr = ctl[C_PRE + t];
  for (int i = blockIdx.x*256 + threadIdx.x; i < M; i += gridDim.x*256) {
    unsigned key = fkey(scores[base + i]);
    if (key > thr) {
      unsigned p = atomicAdd(&ctl[C_CNT + t], 1u);
      if (p < 6000u) decode_store(n, lvl, i, CBASE[lvl] + (int)p, comb, cboxes, cscores);
    } else if (key == thr) {
      unsigned p = atomicAdd(&ctl[C_TIE + t], 1u);
      if (p < 1024u) ctl[C_TIEIDX + t*1024 + p] = (unsigned)i;
    }
  }
}

__global__ void tk_finalize(const float* __restrict__ comb, unsigned* ctl,
                            float* cboxes, float* cscores) {
  int t = blockIdx.x; int lvl = t >> 1, n = t & 1;
  if (threadIdx.x != 0) return;
  int cnt = (int)ctl[C_CNT + t]; if (cnt > 6000) cnt = 6000;
  int need = 6000 - cnt;
  int tc = (int)ctl[C_TIE + t]; if (tc > 1024) tc = 1024;
  unsigned* tb = &ctl[C_TIEIDX + t*1024];
  for (int s = 0; s < need; ++s) {
    unsigned mn = 0xFFFFFFFFu; int mi = -1;
    for (int q = 0; q < tc; ++q) { if (tb[q] < mn) { mn = tb[q]; mi = q; } }
    int slot = CBASE[lvl] + cnt + s;
    if (mi >= 0) {
      tb[mi] = 0xFFFFFFFFu;
      decode_store(n, lvl, (int)mn, slot, comb, cboxes, cscores);
    } else {
      float* cbp = cboxes + ((long)n*MCAND + slot)*4;
      cbp[0]=cbp[1]=cbp[2]=cbp[3]=0.f;
      cscores[(long)n*MCAND + slot] = -3.0e38f;
    }
  }
}

__global__ void decode34(const float* __restrict__ comb, float* cboxes, float* cscores) {
  int n = blockIdx.y;
  int e = blockIdx.x*256 + threadIdx.x;
  if (e >= 3840) return;
  if (e < 3072) decode_store(n, 3, e, 18000 + e, comb, cboxes, cscores);
  else          decode_store(n, 4, e - 3072, 21072 + (e - 3072), comb, cboxes, cscores);
}

// ---------------- NMS: batched sorted-scan, exact greedy equivalence ----------------
#define RCAP 4096
#define NPER 4

__device__ inline unsigned long long shfl_down_u64(unsigned long long v, int o) {
  unsigned hi = __shfl_down((unsigned)(v >> 32), o);
  unsigned lo = __shfl_down((unsigned)v, o);
  return ((unsigned long long)hi << 32) | lo;
}

__global__ __launch_bounds__(1024) void nms_kernel(
    const float* __restrict__ cscores, const float* __restrict__ cboxes,
    float* __restrict__ dout) {
  const int n = blockIdx.x;
  const int tid = threadIdx.x;
  const int lane = tid & 63;
  const int wid = tid >> 6;
  const float* sc = cscores + (long)n*MCAND;
  const float* cb = cboxes + (long)n*MCAND*4;
  float* keepB = dout + KB_OFF + (long)n*4*POSTK;
  float* keepS = dout + KS_OFF + (long)n*POSTK;
  float* keepV = dout + KV_OFF + (long)n*POSTK;

  __shared__ unsigned long long skey[RCAP];
  __shared__ unsigned hist[256];
  __shared__ unsigned sS[8];                    // 0 cnt, 1 kept, 2 qual, 4 prefix
  __shared__ unsigned long long sBest, sCkMask;
  __shared__ unsigned long long wred[16];
  __shared__ float ckbox[64][4];
  __shared__ float ckarea[64];
  __shared__ int cklvl[64];
  __shared__ unsigned char klvl[POSTK];

  // best level-0 candidate (reference's fill value when NMS exhausts)
  unsigned long long best = 0;
  for (int i = tid; i < 6000; i += 1024) {
    unsigned long long v = ((unsigned long long)fkey(sc[i]) << 32) | (unsigned)(~i);
    if (v > best) best = v;
  }
  for (int o = 32; o > 0; o >>= 1) {
    unsigned long long ov = shfl_down_u64(best, o);
    if (ov > best) best = ov;
  }
  if (lane == 0) wred[wid] = best;
  if (tid == 0) sS[1] = 0;
  __syncthreads();
  if (tid == 0) {
    unsigned long long b = 0;
    for (int i = 0; i < 16; ++i) if (wred[i] > b) b = wred[i];
    sBest = b;
  }
  __syncthreads();

  unsigned thrPrev = 0xFFFFFFFFu;
  int processed = 0;
  float msc[NPER], mb[NPER][4], mar[NPER];
  int mlv[NPER], midx[NPER];
  bool mal[NPER];

  for (int batch = 0; batch < 6; ++batch) {
    if (sS[1] >= POSTK || processed >= MCAND) break;
    // ---- radix-select threshold for top-RCAP among keys < thrPrev ----
    unsigned prefix = 0;
    unsigned kcur = RCAP;
    for (int pass = 0; pass < 4; ++pass) {
      if (tid < 256) hist[tid] = 0;
      __syncthreads();
      int shift = 24 - 8*pass;
      for (int i = tid; i < MCAND; i += 1024) {
        unsigned key = fkey(sc[i]);
        if (key < thrPrev && (pass == 0 || (key >> (shift+8)) == prefix))
          atomicAdd(&hist[(key >> shift) & 255], 1u);
      }
      __syncthreads();
      if (tid == 0) {
        if (pass == 0) { unsigned s = 0; for (int d = 0; d < 256; ++d) s += hist[d]; sS[2] = s; }
        if (sS[2] > RCAP) {
          unsigned kc = kcur; int digit = 0;
          for (int d = 255; d >= 0; --d) {
            unsigned c = hist[d];
            if (kc <= c) { digit = d; break; }
            kc -= c;
          }
          kcur = kc;
          prefix = (prefix << 8) | (unsigned)digit;
          sS[4] = prefix;
        } else sS[4] = 0;
      }
      __syncthreads();
      prefix = sS[4];
      if (sS[2] <= RCAP) break;
    }
    unsigned thr = (sS[2] <= RCAP) ? 0u : sS[4];
    // ---- compact into LDS sort array ----
    if (tid == 0) sS[0] = 0;
    for (int i = tid; i < RCAP; i += 1024) skey[i] = 0;
    __syncthreads();
    for (int i = tid; i < MCAND; i += 1024) {
      unsigned key = fkey(sc[i]);
      if (key < thrPrev && key >= thr) {
        unsigned p = atomicAdd(&sS[0], 1u);
        if (p < RCAP) skey[p] = ((unsigned long long)key << 32) | (unsigned)(~i);
      }
    }
    __syncthreads();
    unsigned scnt = sS[0];
    int took = scnt > RCAP ? RCAP : (int)scnt;
    processed += took;
    // ---- bitonic sort, descending ----
    for (int kk = 2; kk <= RCAP; kk <<= 1) {
      for (int jj = kk >> 1; jj > 0; jj >>= 1) {
        for (int i = tid; i < RCAP; i += 1024) {
          int ixj = i ^ jj;
          if (ixj > i) {
            unsigned long long a = skey[i], b = skey[ixj];
            bool up = ((i & kk) == 0);
            if ((a < b) == up) { skey[i] = b; skey[ixj] = a; }
          }
        }
        __syncthreads();
      }
    }
    // ---- unpack to registers (offset boxes: reference IoU arithmetic) ----
    int kt0 = (int)sS[1];
    #pragma unroll
    for (int j = 0; j < NPER; ++j) {
      int rr = tid + j*1024;
      unsigned long long v = skey[rr];
      if (v == 0ull) {
        mal[j] = false; msc[j] = 0.f; mlv[j] = -1; midx[j] = 0; mar[j] = 0.f;
        mb[j][0]=mb[j][1]=mb[j][2]=mb[j][3]=0.f;
        continue;
      }
      unsigned key = (unsigned)(v >> 32);
      int idx = (int)(~(unsigned)v);
      midx[j] = idx;
      msc[j] = unfkey(key);
      int lv = idx < 6000 ? 0 : idx < 12000 ? 1 : idx < 18000 ? 2 : idx < 21072 ? 3 : 4;
      mlv[j] = lv;
      float off = 2000.f * (float)lv;
      mb[j][0] = cb[idx*4+0] + off;
      mb[j][1] = cb[idx*4+1] + off;
      mb[j][2] = cb[idx*4+2] + off;
      mb[j][3] = cb[idx*4+3] + off;
      mar[j] = (mb[j][2]-mb[j][0]) * (mb[j][3]-mb[j][1]);
      mal[j] = true;
    }
    // ---- pre-suppress vs kept from previous batches ----
    if (kt0 > 0) {
      for (int j = 0; j < NPER; ++j) {
        if (!mal[j]) continue;
        for (int k2 = 0; k2 < kt0; ++k2) {
          if ((int)klvl[k2] != mlv[j]) continue;
          float off = 2000.f * (float)mlv[j];
          float kx1 = keepB[k2*4+0] + off, ky1 = keepB[k2*4+1] + off;
          float kx2 = keepB[k2*4+2] + off, ky2 = keepB[k2*4+3] + off;
          float kar = (kx2-kx1)*(ky2-ky1);
          float ix1 = fmaxf(kx1, mb[j][0]), iy1 = fmaxf(ky1, mb[j][1]);
          float ix2 = fminf(kx2, mb[j][2]), iy2 = fminf(ky2, mb[j][3]);
          float inter = fmaxf(ix2-ix1, 0.f) * fmaxf(iy2-iy1, 0.f);
          float iou = inter / (kar + mar[j] - inter + 1e-9f);
          if (iou > 0.7f) { mal[j] = false; break; }
        }
      }
    }
    __syncthreads();
    // ---- chunked greedy scan over sorted order ----
    for (int c = 0; c < RCAP/64; ++c) {
      int kt = (int)sS[1];
      if (kt >= POSTK) break;
      if (wid == (c & 15)) {
        int j = c >> 4;
        unsigned long long aliveM = __ballot(mal[j]);
        unsigned long long keptM = 0;
        int allowed = POSTK - kt;
        for (int b = 0; b < 64; ++b) {
          if ((int)__popcll(keptM) >= allowed) break;
          if (!((aliveM >> b) & 1)) continue;
          keptM |= (1ull << b);
          float bx1 = __shfl(mb[j][0], b), by1 = __shfl(mb[j][1], b);
          float bx2 = __shfl(mb[j][2], b), by2 = __shfl(mb[j][3], b);
          float bar = __shfl(mar[j], b);
          int blv = __shfl(mlv[j], b);
          bool sup = false;
          if (lane > b && ((aliveM >> lane) & 1) && mlv[j] == blv) {
            float ix1 = fmaxf(bx1, mb[j][0]), iy1 = fmaxf(by1, mb[j][1]);
            float ix2 = fminf(bx2, mb[j][2]), iy2 = fminf(by2, mb[j][3]);
            float inter = fmaxf(ix2-ix1, 0.f) * fmaxf(iy2-iy1, 0.f);
            float iou = inter / (bar + mar[j] - inter + 1e-9f);
            sup = iou > 0.7f;
          }
          aliveM &= ~__ballot(sup);
        }
        bool isK = (keptM >> lane) & 1;
        if (isK) {
          int ord = kt + (int)__popcll(keptM & ((1ull << lane) - 1ull));
          if (ord < POSTK) {
            int idx = midx[j];
            keepB[ord*4+0] = cb[idx*4+0];
            keepB[ord*4+1] = cb[idx*4+1];
            keepB[ord*4+2] = cb[idx*4+2];
            keepB[ord*4+3] = cb[idx*4+3];
            keepS[ord] = msc[j];
            keepV[ord] = 1.f;
            klvl[ord] = (unsigned char)mlv[j];
          }
          ckbox[lane][0] = mb[j][0]; ckbox[lane][1] = mb[j][1];
          ckbox[lane][2] = mb[j][2]; ckbox[lane][3] = mb[j][3];
          ckarea[lane] = mar[j]; cklvl[lane] = mlv[j];
        }
        if (lane == 0) {
          sCkMask = keptM;
          sS[1] = (unsigned)(kt + (int)__popcll(keptM));
        }
        mal[j] = false;   // chunk fully resolved
      }
      __syncthreads();
      unsigned long long km = sCkMask;
      if (km) {
        int cEnd = c*64 + 63;
        #pragma unroll
        for (int j = 0; j < NPER; ++j) {
          int rr = tid + j*1024;
          if (rr <= cEnd || !mal[j]) continue;
          for (unsigned long long m = km; m; m &= (m-1)) {
            int b = __ffsll((unsigned long long)m) - 1;
            if (cklvl[b] != mlv[j]) continue;
            float ix1 = fmaxf(ckbox[b][0], mb[j][0]), iy1 = fmaxf(ckbox[b][1], mb[j][1]);
            float ix2 = fminf(ckbox[b][2], mb[j][2]), iy2 = fminf(ckbox[b][3], mb[j][3]);
            float inter = fmaxf(ix2-ix1, 0.f) * fmaxf(iy2-iy1, 0.f);
            float iou = inter / (ckarea[b] + mar[j] - inter + 1e-9f);
            if (iou > 0.7f) { mal[j] = false; break; }
          }
        }
      }
      __syncthreads();
    }
    if (thr == 0u) processed = MCAND;
    thrPrev = thr;
    __syncthreads();
  }
  __syncthreads();
  // ---- fill remaining slots (reference: argmax of all -inf -> index 0) ----
  int kt = (int)sS[1];
  unsigned long long bb = sBest;
  int bidx = (int)(~(unsigned)bb);
  float b0 = cb[bidx*4+0], b1 = cb[bidx*4+1], b2 = cb[bidx*4+2], b3 = cb[bidx*4+3];
  float bsc = sc[bidx];
  for (int s2 = kt + tid; s2 < POSTK; s2 += 1024) {
    keepB[s2*4+0]=b0; keepB[s2*4+1]=b1; keepB[s2*4+2]=b2; keepB[s2*4+3]=b3;
    keepS[s2] = bsc; keepV[s2] = 0.f;
  }
}

// ---------------- launcher ----------------
extern "C" void kernel_launch(void* const* d_in, const int* in_sizes, int n_in,
                              void* d_out, int out_size, void* d_ws, size_t ws_size,
                              hipStream_t stream) {
  const float* feats[5];
  for (int i = 0; i < 5; ++i) feats[i] = (const float*)d_in[i];
  const float* conv_w  = (const float*)d_in[5];
  const float* conv_b  = (const float*)d_in[6];
  const float* obj_w   = (const float*)d_in[7];
  const float* obj_b   = (const float*)d_in[8];
  const float* delta_w = (const float*)d_in[9];
  const float* delta_b = (const float*)d_in[10];
  float* out = (float*)d_out;
  float* ws = (float*)d_ws;
  float* t       = ws + WS_T;
  float* scores  = ws + WS_SC;
  float* cboxes  = ws + WS_CB;
  float* cscores = ws + WS_CS;
  unsigned* ctl  = (unsigned*)(ws + WS_CTL);

  static const int LWh[5]    = {256,128,64,32,16};
  static const int LBASEh[5] = {0,196608,245760,258048,261120};

  init_ctl<<<dim3(1), dim3(256), 0, stream>>>(ctl);
  for (int n = 0; n < 2; ++n) {
    for (int lvl = 0; lvl < 5; ++lvl) {
      int H = LWh[lvl], W = LWh[lvl], HW = H*W;
      conv3x3_relu<<<dim3(W/16, H/4, 4), dim3(256), 0, stream>>>(
          feats[lvl] + (long)n*256*HW, conv_w, conv_b, t, H, W);
      int hb = (HW + 1023) / 1024;
      heads1x1<<<dim3(hb), dim3(256), 0, stream>>>(
          t, obj_w, obj_b, delta_w, delta_b, out, scores, HW, LBASEh[lvl], n);
    }
  }
  for (int p = 0; p < 4; ++p) {
    tk_hist<<<dim3(48,6), dim3(256), 0, stream>>>(scores, ctl, p);
    tk_pick<<<dim3(6), dim3(256), 0, stream>>>(ctl);
  }
  tk_compact<<<dim3(48,6), dim3(256), 0, stream>>>(scores, out, ctl, cboxes, cscores);
  tk_finalize<<<dim3(6), dim3(64), 0, stream>>>(out, ctl, cboxes, cscores);
  decode34<<<dim3(15,2), dim3(256), 0, stream>>>(out, cboxes, cscores);
  nms_kernel<<<dim3(2), dim3(1024), 0, stream>>>(cscores, cboxes, out);
}

// Round 2
// 8918.111 us; speedup vs baseline: 1.3959x; 1.3959x over previous
//
#include <hip/hip_runtime.h>
#include <math.h>

// ---------------- problem constants ----------------
#define ATOT 261888          // sum over levels of H*W*3
#define MCAND 21840          // 6000+6000+6000+3072+768 candidates per image
#define POSTK 1000
#define CMB (2*ATOT*5)       // combined output floats = 2618880
#define KB_OFF CMB           // keep_boxes offset in d_out
#define KS_OFF (CMB+8000)    // keep_scores
#define KV_OFF (CMB+10000)   // valid
#define SCALE_CLAMP 4.135166556742356f

// ---------------- ws layout (float units) ----------------
#define WS_T   0
#define WS_SC  (256*65536)            // 16777216  (t buffer: one image, largest level)
#define WS_CB  (WS_SC + 2*ATOT)       // scores: 2*261888
#define WS_CS  (WS_CB + 2*MCAND*4)    // cand boxes
#define WS_CTL (WS_CS + 2*MCAND)      // cand scores -> then ctl (u32)

// ctl indices (u32)
#define C_PRE 0
#define C_KCUR 6
#define C_CNT 12
#define C_TIE 18
#define C_GH 32
#define C_TIEIDX (C_GH + 6*256)
#define CTL_SIZE (C_TIEIDX + 6*1024)
#define WS_WP  (WS_CTL + CTL_SIZE)    // prepped conv weights: [ci*9+kk][256 oc] = 589824 floats

__device__ const int LW[5]    = {256,128,64,32,16};
__device__ const int LM[5]    = {196608,49152,12288,3072,768};
__device__ const int LBASE[5] = {0,196608,245760,258048,261120};
__device__ const int LSTR[5]  = {4,8,16,32,64};
__device__ const int LSZ[5]   = {32,64,128,256,512};
__device__ const int CBASE[5] = {0,6000,12000,18000,21072};

__device__ inline unsigned fkey(float f) {
  unsigned u = __float_as_uint(f);
  return u ^ (unsigned)(((int)u >> 31) | 0x80000000);
}
__device__ inline float unfkey(unsigned k) {
  unsigned u = (k & 0x80000000u) ? (k ^ 0x80000000u) : ~k;
  return __uint_as_float(u);
}

// ---------------- weight prep: wgt[oc][ci][kk] -> wp[(ci*9+kk)][oc] ----------------
__global__ __launch_bounds__(256) void wprep_kernel(const float* __restrict__ wgt,
                                                    float* __restrict__ wp) {
  int o = blockIdx.x*256 + threadIdx.x;
  if (o >= 2304*256) return;
  int ko = o & 255; int rk = o >> 8;          // rk = ci*9+kk
  int ci = rk / 9;  int kk = rk - ci*9;
  wp[o] = wgt[(ko*256 + ci)*9 + kk];
}

// ---------------- conv3x3 + bias + relu (v2) ----------------
// block 256, tile: 64 oc x (16x16 px). thread: 8 oc x 8 px. grid (W/16, H/16, 4).
#define CHK 8
__global__ __launch_bounds__(256,4) void conv3x3_relu(
    const float* __restrict__ in, const float* __restrict__ wp,
    const float* __restrict__ bias, float* __restrict__ outp, int H, int W) {
  const int tid = threadIdx.x;
  const int x0 = blockIdx.x * 16;
  const int y0 = blockIdx.y * 16;
  const int koB = blockIdx.z * 64;
  const int HW = H * W;
  const int oc_g = tid >> 5;           // 0..7 -> oc8 = oc_g*8
  const int pg   = tid & 31;
  const int row  = pg >> 1;            // 0..15
  const int col0 = (pg & 1) << 3;      // 0 or 8
  __shared__ float inS[CHK][18][20];   // stride 20: 16B-aligned rows, <=2-way banks
  __shared__ float wS[CHK*9][64];
  float acc[8][8] = {};
  for (int c0 = 0; c0 < 256; c0 += CHK) {
    // stage input tile (18x18 halo per ci)
    for (int i = tid; i < CHK*18*18; i += 256) {
      int ci = i / 324; int r = i - ci*324; int iy = r / 18; int ix = r - iy*18;
      int gy = y0 + iy - 1, gx = x0 + ix - 1;
      float v = 0.f;
      if (gy >= 0 && gy < H && gx >= 0 && gx < W) v = in[(c0+ci)*HW + gy*W + gx];
      inS[ci][iy][ix] = v;
    }
    // stage weights: contiguous float4 from prepped layout
    for (int i = tid; i < CHK*9*16; i += 256) {
      int rkk = i >> 4; int c4 = (i & 15) << 2;
      *(float4*)&wS[rkk][c4] = *(const float4*)&wp[(c0*9 + rkk)*256 + koB + c4];
    }
    __syncthreads();
    #pragma unroll
    for (int ci = 0; ci < CHK; ++ci) {
      #pragma unroll
      for (int kh = 0; kh < 3; ++kh) {
        float iv[10];
        float4 t0 = *(const float4*)&inS[ci][row+kh][col0];
        float4 t1 = *(const float4*)&inS[ci][row+kh][col0+4];
        float2 t2 = *(const float2*)&inS[ci][row+kh][col0+8];
        iv[0]=t0.x; iv[1]=t0.y; iv[2]=t0.z; iv[3]=t0.w;
        iv[4]=t1.x; iv[5]=t1.y; iv[6]=t1.z; iv[7]=t1.w;
        iv[8]=t2.x; iv[9]=t2.y;
        #pragma unroll
        for (int kw = 0; kw < 3; ++kw) {
          const int rr = ci*9 + kh*3 + kw;
          float4 w0 = *(const float4*)&wS[rr][oc_g*8];
          float4 w1 = *(const float4*)&wS[rr][oc_g*8+4];
          float wv[8] = {w0.x,w0.y,w0.z,w0.w,w1.x,w1.y,w1.z,w1.w};
          #pragma unroll
          for (int k = 0; k < 8; ++k)
            #pragma unroll
            for (int j = 0; j < 8; ++j)
              acc[k][j] += wv[k] * iv[kw+j];
        }
      }
    }
    __syncthreads();
  }
  const int oy = y0 + row, ox = x0 + col0;
  #pragma unroll
  for (int k = 0; k < 8; ++k) {
    int oc = koB + oc_g*8 + k;
    float bb = bias[oc];
    float4 v0, v1;
    v0.x = fmaxf(acc[k][0]+bb, 0.f); v0.y = fmaxf(acc[k][1]+bb, 0.f);
    v0.z = fmaxf(acc[k][2]+bb, 0.f); v0.w = fmaxf(acc[k][3]+bb, 0.f);
    v1.x = fmaxf(acc[k][4]+bb, 0.f); v1.y = fmaxf(acc[k][5]+bb, 0.f);
    v1.z = fmaxf(acc[k][6]+bb, 0.f); v1.w = fmaxf(acc[k][7]+bb, 0.f);
    *(float4*)&outp[oc*HW + oy*W + ox]     = v0;
    *(float4*)&outp[oc*HW + oy*W + ox + 4] = v1;
  }
}

// ---------------- 1x1 heads: writes combined + scores ----------------
__global__ __launch_bounds__(256) void heads1x1(
    const float* __restrict__ t, const float* __restrict__ ow, const float* __restrict__ ob,
    const float* __restrict__ dw, const float* __restrict__ db,
    float* __restrict__ comb, float* __restrict__ scores, int HW, int lbase, int n) {
  __shared__ float wS[15][256];
  const int tid = threadIdx.x;
  for (int i = tid; i < 3*256; i += 256) wS[i>>8][i&255] = ow[i];
  for (int i = tid; i < 12*256; i += 256) wS[3+(i>>8)][i&255] = dw[i];
  __syncthreads();
  int p0 = (blockIdx.x*256 + tid) * 4;
  if (p0 >= HW) return;
  float acc[15][4] = {};
  for (int c = 0; c < 256; ++c) {
    float4 v = *(const float4*)&t[c*HW + p0];
    float vv[4] = {v.x, v.y, v.z, v.w};
    #pragma unroll
    for (int k = 0; k < 15; ++k) {
      float w = wS[k][c];
      #pragma unroll
      for (int j = 0; j < 4; ++j) acc[k][j] += w * vv[j];
    }
  }
  float obv[3]; for (int i2 = 0; i2 < 3; ++i2) obv[i2] = ob[i2];
  float dbv[12]; for (int i2 = 0; i2 < 12; ++i2) dbv[i2] = db[i2];
  for (int j = 0; j < 4; ++j) {
    int pos = p0 + j;
    long base = (long)n*ATOT + lbase + (long)pos*3;
    #pragma unroll
    for (int a = 0; a < 3; ++a) {
      float lg = acc[a][j] + obv[a];
      comb[(base+a)*5] = lg;
      scores[(long)n*ATOT + lbase + pos*3 + a] = lg;
      #pragma unroll
      for (int q = 0; q < 4; ++q)
        comb[(base+a)*5 + 1 + q] = acc[3 + a*4 + q][j] + dbv[a*4+q];
    }
  }
}

// ---------------- decode (matches reference fp32 ops; anchors in f64 then cast) ----
__device__ void decode_store(int n, int lvl, int idx, int slot,
                             const float* comb, float* cboxes, float* cscores) {
  int W = LW[lvl];
  int a = idx % 3; int p = idx / 3;
  int wx = p % W, hy = p / W;
  double r = (a == 0) ? 0.5 : (a == 1) ? 1.0 : 2.0;
  double sz = (double)LSZ[lvl];
  double wsd = sqrt(sz*sz/r);
  double hsd = wsd * r;
  double cxd = (double)(wx * LSTR[lvl]);
  double cyd = (double)(hy * LSTR[lvl]);
  float ax1 = (float)(cxd - 0.5*wsd), ay1 = (float)(cyd - 0.5*hsd);
  float ax2 = (float)(cxd + 0.5*wsd), ay2 = (float)(cyd + 0.5*hsd);
  float aw = ax2 - ax1, ah = ay2 - ay1;
  float acx = ax1 + 0.5f*aw, acy = ay1 + 0.5f*ah;
  long g = (long)n*ATOT + LBASE[lvl] + idx;
  const float* cm = comb + g*5;
  float sc = cm[0];
  float dx = cm[1], dy = cm[2], dwv = cm[3], dhv = cm[4];
  dwv = fminf(dwv, SCALE_CLAMP); dhv = fminf(dhv, SCALE_CLAMP);
  float pcx = __fadd_rn(__fmul_rn(dx, aw), acx);
  float pcy = __fadd_rn(__fmul_rn(dy, ah), acy);
  float pw = __fmul_rn(expf(dwv), aw);
  float ph = __fmul_rn(expf(dhv), ah);
  float x1 = __fsub_rn(pcx, 0.5f*pw), y1 = __fsub_rn(pcy, 0.5f*ph);
  float x2 = __fadd_rn(pcx, 0.5f*pw), y2 = __fadd_rn(pcy, 0.5f*ph);
  x1 = fminf(fmaxf(x1, 0.f), 1024.f);
  y1 = fminf(fmaxf(y1, 0.f), 1024.f);
  x2 = fminf(fmaxf(x2, 0.f), 1024.f);
  y2 = fminf(fmaxf(y2, 0.f), 1024.f);
  float* cbp = cboxes + ((long)n*MCAND + slot)*4;
  cbp[0]=x1; cbp[1]=y1; cbp[2]=x2; cbp[3]=y2;
  cscores[(long)n*MCAND + slot] = sc;
}

// ---------------- radix top-k (k=6000) for levels 0..2 x 2 images ----------------
__global__ void init_ctl(unsigned* ctl) {
  for (int i = threadIdx.x; i < CTL_SIZE; i += 256) ctl[i] = 0;
  __syncthreads();
  if (threadIdx.x < 6) ctl[C_KCUR + threadIdx.x] = 6000;
}

__global__ __launch_bounds__(256) void tk_hist(const float* __restrict__ scores,
                                               unsigned* ctl, int pass) {
  int t = blockIdx.y; int lvl = t >> 1, n = t & 1;
  int M = LM[lvl]; long base = (long)n*ATOT + LBASE[lvl];
  __shared__ unsigned h[256];
  h[threadIdx.x] = 0;
  __syncthreads();
  unsigned prefix = ctl[C_PRE + t];
  int shift = 24 - 8*pass;
  for (int i = blockIdx.x*256 + threadIdx.x; i < M; i += gridDim.x*256) {
    unsigned key = fkey(scores[base + i]);
    if (pass == 0 || (key >> (shift+8)) == prefix)
      atomicAdd(&h[(key >> shift) & 255], 1u);
  }
  __syncthreads();
  if (h[threadIdx.x]) atomicAdd(&ctl[C_GH + t*256 + threadIdx.x], h[threadIdx.x]);
}

__global__ __launch_bounds__(256) void tk_pick(unsigned* ctl) {
  int t = blockIdx.x;
  if (threadIdx.x == 0) {
    unsigned kcur = ctl[C_KCUR + t];
    int digit = 0;
    for (int d = 255; d >= 0; --d) {
      unsigned c = ctl[C_GH + t*256 + d];
      if (kcur <= c) { digit = d; break; }
      kcur -= c;
    }
    ctl[C_KCUR + t] = kcur;
    ctl[C_PRE + t] = (ctl[C_PRE + t] << 8) | (unsigned)digit;
  }
  __syncthreads();
  ctl[C_GH + t*256 + threadIdx.x] = 0;
}

__global__ __launch_bounds__(256) void tk_compact(const float* __restrict__ scores,
    const float* __restrict__ comb, unsigned* ctl, float* cboxes, float* cscores) {
  int t = blockIdx.y; int lvl = t >> 1, n = t & 1;
  int M = LM[lvl]; long base = (long)n*ATOT + LBASE[lvl];
  unsigned thr = ctl[C_PRE + t];
  for (int i = blockIdx.x*256 + threadIdx.x; i < M; i += gridDim.x*256) {
    unsigned key = fkey(scores[base + i]);
    if (key > thr) {
      unsigned p = atomicAdd(&ctl[C_CNT + t], 1u);
      if (p < 6000u) decode_store(n, lvl, i, CBASE[lvl] + (int)p, comb, cboxes, cscores);
    } else if (key == thr) {
      unsigned p = atomicAdd(&ctl[C_TIE + t], 1u);
      if (p < 1024u) ctl[C_TIEIDX + t*1024 + p] = (unsigned)i;
    }
  }
}

__global__ void tk_finalize(const float* __restrict__ comb, unsigned* ctl,
                            float* cboxes, float* cscores) {
  int t = blockIdx.x; int lvl = t >> 1, n = t & 1;
  if (threadIdx.x != 0) return;
  int cnt = (int)ctl[C_CNT + t]; if (cnt > 6000) cnt = 6000;
  int need = 6000 - cnt;
  int tc = (int)ctl[C_TIE + t]; if (tc > 1024) tc = 1024;
  unsigned* tb = &ctl[C_TIEIDX + t*1024];
  for (int s = 0; s < need; ++s) {
    unsigned mn = 0xFFFFFFFFu; int mi = -1;
    for (int q = 0; q < tc; ++q) { if (tb[q] < mn) { mn = tb[q]; mi = q; } }
    int slot = CBASE[lvl] + cnt + s;
    if (mi >= 0) {
      tb[mi] = 0xFFFFFFFFu;
      decode_store(n, lvl, (int)mn, slot, comb, cboxes, cscores);
    } else {
      float* cbp = cboxes + ((long)n*MCAND + slot)*4;
      cbp[0]=cbp[1]=cbp[2]=cbp[3]=0.f;
      cscores[(long)n*MCAND + slot] = -3.0e38f;
    }
  }
}

__global__ void decode34(const float* __restrict__ comb, float* cboxes, float* cscores) {
  int n = blockIdx.y;
  int e = blockIdx.x*256 + threadIdx.x;
  if (e >= 3840) return;
  if (e < 3072) decode_store(n, 3, e, 18000 + e, comb, cboxes, cscores);
  else          decode_store(n, 4, e - 3072, 21072 + (e - 3072), comb, cboxes, cscores);
}

// ---------------- NMS: batched sorted-scan, exact greedy equivalence ----------------
#define RCAP 4096
#define NPER 4

__device__ inline unsigned long long shfl_down_u64(unsigned long long v, int o) {
  unsigned hi = __shfl_down((unsigned)(v >> 32), o);
  unsigned lo = __shfl_down((unsigned)v, o);
  return ((unsigned long long)hi << 32) | lo;
}

__global__ __launch_bounds__(1024) void nms_kernel(
    const float* __restrict__ cscores, const float* __restrict__ cboxes,
    float* __restrict__ dout) {
  const int n = blockIdx.x;
  const int tid = threadIdx.x;
  const int lane = tid & 63;
  const int wid = tid >> 6;
  const float* sc = cscores + (long)n*MCAND;
  const float* cb = cboxes + (long)n*MCAND*4;
  float* keepB = dout + KB_OFF + (long)n*4*POSTK;
  float* keepS = dout + KS_OFF + (long)n*POSTK;
  float* keepV = dout + KV_OFF + (long)n*POSTK;

  __shared__ unsigned long long skey[RCAP];
  __shared__ unsigned hist[256];
  __shared__ unsigned sS[8];
  __shared__ unsigned long long sBest, sCkMask;
  __shared__ unsigned long long wred[16];
  __shared__ float ckbox[64][4];
  __shared__ float ckarea[64];
  __shared__ int cklvl[64];
  __shared__ unsigned char klvl[POSTK];

  unsigned long long best = 0;
  for (int i = tid; i < 6000; i += 1024) {
    unsigned long long v = ((unsigned long long)fkey(sc[i]) << 32) | (unsigned)(~i);
    if (v > best) best = v;
  }
  for (int o = 32; o > 0; o >>= 1) {
    unsigned long long ov = shfl_down_u64(best, o);
    if (ov > best) best = ov;
  }
  if (lane == 0) wred[wid] = best;
  if (tid == 0) sS[1] = 0;
  __syncthreads();
  if (tid == 0) {
    unsigned long long b = 0;
    for (int i = 0; i < 16; ++i) if (wred[i] > b) b = wred[i];
    sBest = b;
  }
  __syncthreads();

  unsigned thrPrev = 0xFFFFFFFFu;
  int processed = 0;
  float msc[NPER], mb[NPER][4], mar[NPER];
  int mlv[NPER], midx[NPER];
  bool mal[NPER];

  for (int batch = 0; batch < 6; ++batch) {
    if (sS[1] >= POSTK || processed >= MCAND) break;
    unsigned prefix = 0;
    unsigned kcur = RCAP;
    for (int pass = 0; pass < 4; ++pass) {
      if (tid < 256) hist[tid] = 0;
      __syncthreads();
      int shift = 24 - 8*pass;
      for (int i = tid; i < MCAND; i += 1024) {
        unsigned key = fkey(sc[i]);
        if (key < thrPrev && (pass == 0 || (key >> (shift+8)) == prefix))
          atomicAdd(&hist[(key >> shift) & 255], 1u);
      }
      __syncthreads();
      if (tid == 0) {
        if (pass == 0) { unsigned s = 0; for (int d = 0; d < 256; ++d) s += hist[d]; sS[2] = s; }
        if (sS[2] > RCAP) {
          unsigned kc = kcur; int digit = 0;
          for (int d = 255; d >= 0; --d) {
            unsigned c = hist[d];
            if (kc <= c) { digit = d; break; }
            kc -= c;
          }
          kcur = kc;
          prefix = (prefix << 8) | (unsigned)digit;
          sS[4] = prefix;
        } else sS[4] = 0;
      }
      __syncthreads();
      prefix = sS[4];
      if (sS[2] <= RCAP) break;
    }
    unsigned thr = (sS[2] <= RCAP) ? 0u : sS[4];
    if (tid == 0) sS[0] = 0;
    for (int i = tid; i < RCAP; i += 1024) skey[i] = 0;
    __syncthreads();
    for (int i = tid; i < MCAND; i += 1024) {
      unsigned key = fkey(sc[i]);
      if (key < thrPrev && key >= thr) {
        unsigned p = atomicAdd(&sS[0], 1u);
        if (p < RCAP) skey[p] = ((unsigned long long)key << 32) | (unsigned)(~i);
      }
    }
    __syncthreads();
    unsigned scnt = sS[0];
    int took = scnt > RCAP ? RCAP : (int)scnt;
    processed += took;
    for (int kk = 2; kk <= RCAP; kk <<= 1) {
      for (int jj = kk >> 1; jj > 0; jj >>= 1) {
        for (int i = tid; i < RCAP; i += 1024) {
          int ixj = i ^ jj;
          if (ixj > i) {
            unsigned long long a = skey[i], b = skey[ixj];
            bool up = ((i & kk) == 0);
            if ((a < b) == up) { skey[i] = b; skey[ixj] = a; }
          }
        }
        __syncthreads();
      }
    }
    int kt0 = (int)sS[1];
    #pragma unroll
    for (int j = 0; j < NPER; ++j) {
      int rr = tid + j*1024;
      unsigned long long v = skey[rr];
      if (v == 0ull) {
        mal[j] = false; msc[j] = 0.f; mlv[j] = -1; midx[j] = 0; mar[j] = 0.f;
        mb[j][0]=mb[j][1]=mb[j][2]=mb[j][3]=0.f;
        continue;
      }
      unsigned key = (unsigned)(v >> 32);
      int idx = (int)(~(unsigned)v);
      midx[j] = idx;
      msc[j] = unfkey(key);
      int lv = idx < 6000 ? 0 : idx < 12000 ? 1 : idx < 18000 ? 2 : idx < 21072 ? 3 : 4;
      mlv[j] = lv;
      float off = 2000.f * (float)lv;
      mb[j][0] = cb[idx*4+0] + off;
      mb[j][1] = cb[idx*4+1] + off;
      mb[j][2] = cb[idx*4+2] + off;
      mb[j][3] = cb[idx*4+3] + off;
      mar[j] = (mb[j][2]-mb[j][0]) * (mb[j][3]-mb[j][1]);
      mal[j] = true;
    }
    if (kt0 > 0) {
      for (int j = 0; j < NPER; ++j) {
        if (!mal[j]) continue;
        for (int k2 = 0; k2 < kt0; ++k2) {
          if ((int)klvl[k2] != mlv[j]) continue;
          float off = 2000.f * (float)mlv[j];
          float kx1 = keepB[k2*4+0] + off, ky1 = keepB[k2*4+1] + off;
          float kx2 = keepB[k2*4+2] + off, ky2 = keepB[k2*4+3] + off;
          float kar = (kx2-kx1)*(ky2-ky1);
          float ix1 = fmaxf(kx1, mb[j][0]), iy1 = fmaxf(ky1, mb[j][1]);
          float ix2 = fminf(kx2, mb[j][2]), iy2 = fminf(ky2, mb[j][3]);
          float inter = fmaxf(ix2-ix1, 0.f) * fmaxf(iy2-iy1, 0.f);
          float iou = inter / (kar + mar[j] - inter + 1e-9f);
          if (iou > 0.7f) { mal[j] = false; break; }
        }
      }
    }
    __syncthreads();
    for (int c = 0; c < RCAP/64; ++c) {
      int kt = (int)sS[1];
      if (kt >= POSTK) break;
      if (wid == (c & 15)) {
        int j = c >> 4;
        unsigned long long aliveM = __ballot(mal[j]);
        unsigned long long keptM = 0;
        int allowed = POSTK - kt;
        for (int b = 0; b < 64; ++b) {
          if ((int)__popcll(keptM) >= allowed) break;
          if (!((aliveM >> b) & 1)) continue;
          keptM |= (1ull << b);
          float bx1 = __shfl(mb[j][0], b), by1 = __shfl(mb[j][1], b);
          float bx2 = __shfl(mb[j][2], b), by2 = __shfl(mb[j][3], b);
          float bar = __shfl(mar[j], b);
          int blv = __shfl(mlv[j], b);
          bool sup = false;
          if (lane > b && ((aliveM >> lane) & 1) && mlv[j] == blv) {
            float ix1 = fmaxf(bx1, mb[j][0]), iy1 = fmaxf(by1, mb[j][1]);
            float ix2 = fminf(bx2, mb[j][2]), iy2 = fminf(by2, mb[j][3]);
            float inter = fmaxf(ix2-ix1, 0.f) * fmaxf(iy2-iy1, 0.f);
            float iou = inter / (bar + mar[j] - inter + 1e-9f);
            sup = iou > 0.7f;
          }
          aliveM &= ~__ballot(sup);
        }
        bool isK = (keptM >> lane) & 1;
        if (isK) {
          int ord = kt + (int)__popcll(keptM & ((1ull << lane) - 1ull));
          if (ord < POSTK) {
            int idx = midx[j];
            keepB[ord*4+0] = cb[idx*4+0];
            keepB[ord*4+1] = cb[idx*4+1];
            keepB[ord*4+2] = cb[idx*4+2];
            keepB[ord*4+3] = cb[idx*4+3];
            keepS[ord] = msc[j];
            keepV[ord] = 1.f;
            klvl[ord] = (unsigned char)mlv[j];
          }
          ckbox[lane][0] = mb[j][0]; ckbox[lane][1] = mb[j][1];
          ckbox[lane][2] = mb[j][2]; ckbox[lane][3] = mb[j][3];
          ckarea[lane] = mar[j]; cklvl[lane] = mlv[j];
        }
        if (lane == 0) {
          sCkMask = keptM;
          sS[1] = (unsigned)(kt + (int)__popcll(keptM));
        }
        mal[j] = false;
      }
      __syncthreads();
      unsigned long long km = sCkMask;
      if (km) {
        int cEnd = c*64 + 63;
        #pragma unroll
        for (int j = 0; j < NPER; ++j) {
          int rr = tid + j*1024;
          if (rr <= cEnd || !mal[j]) continue;
          for (unsigned long long m = km; m; m &= (m-1)) {
            int b = __ffsll((unsigned long long)m) - 1;
            if (cklvl[b] != mlv[j]) continue;
            float ix1 = fmaxf(ckbox[b][0], mb[j][0]), iy1 = fmaxf(ckbox[b][1], mb[j][1]);
            float ix2 = fminf(ckbox[b][2], mb[j][2]), iy2 = fminf(ckbox[b][3], mb[j][3]);
            float inter = fmaxf(ix2-ix1, 0.f) * fmaxf(iy2-iy1, 0.f);
            float iou = inter / (ckarea[b] + mar[j] - inter + 1e-9f);
            if (iou > 0.7f) { mal[j] = false; break; }
          }
        }
      }
      __syncthreads();
    }
    if (thr == 0u) processed = MCAND;
    thrPrev = thr;
    __syncthreads();
  }
  __syncthreads();
  int kt = (int)sS[1];
  unsigned long long bb = sBest;
  int bidx = (int)(~(unsigned)bb);
  float b0 = cb[bidx*4+0], b1 = cb[bidx*4+1], b2 = cb[bidx*4+2], b3 = cb[bidx*4+3];
  float bsc = sc[bidx];
  for (int s2 = kt + tid; s2 < POSTK; s2 += 1024) {
    keepB[s2*4+0]=b0; keepB[s2*4+1]=b1; keepB[s2*4+2]=b2; keepB[s2*4+3]=b3;
    keepS[s2] = bsc; keepV[s2] = 0.f;
  }
}

// ---------------- launcher ----------------
extern "C" void kernel_launch(void* const* d_in, const int* in_sizes, int n_in,
                              void* d_out, int out_size, void* d_ws, size_t ws_size,
                              hipStream_t stream) {
  const float* feats[5];
  for (int i = 0; i < 5; ++i) feats[i] = (const float*)d_in[i];
  const float* conv_w  = (const float*)d_in[5];
  const float* conv_b  = (const float*)d_in[6];
  const float* obj_w   = (const float*)d_in[7];
  const float* obj_b   = (const float*)d_in[8];
  const float* delta_w = (const float*)d_in[9];
  const float* delta_b = (const float*)d_in[10];
  float* out = (float*)d_out;
  float* ws = (float*)d_ws;
  float* t       = ws + WS_T;
  float* scores  = ws + WS_SC;
  float* cboxes  = ws + WS_CB;
  float* cscores = ws + WS_CS;
  unsigned* ctl  = (unsigned*)(ws + WS_CTL);
  float* wp      = ws + WS_WP;

  static const int LWh[5]    = {256,128,64,32,16};
  static const int LBASEh[5] = {0,196608,245760,258048,261120};

  wprep_kernel<<<dim3(2304), dim3(256), 0, stream>>>(conv_w, wp);
  init_ctl<<<dim3(1), dim3(256), 0, stream>>>(ctl);
  for (int n = 0; n < 2; ++n) {
    for (int lvl = 0; lvl < 5; ++lvl) {
      int H = LWh[lvl], W = LWh[lvl], HW = H*W;
      conv3x3_relu<<<dim3(W/16, H/16, 4), dim3(256), 0, stream>>>(
          feats[lvl] + (long)n*256*HW, wp, conv_b, t, H, W);
      int hb = (HW + 1023) / 1024;
      heads1x1<<<dim3(hb), dim3(256), 0, stream>>>(
          t, obj_w, obj_b, delta_w, delta_b, out, scores, HW, LBASEh[lvl], n);
    }
  }
  for (int p = 0; p < 4; ++p) {
    tk_hist<<<dim3(48,6), dim3(256), 0, stream>>>(scores, ctl, p);
    tk_pick<<<dim3(6), dim3(256), 0, stream>>>(ctl);
  }
  tk_compact<<<dim3(48,6), dim3(256), 0, stream>>>(scores, out, ctl, cboxes, cscores);
  tk_finalize<<<dim3(6), dim3(64), 0, stream>>>(out, ctl, cboxes, cscores);
  decode34<<<dim3(15,2), dim3(256), 0, stream>>>(out, cboxes, cscores);
  nms_kernel<<<dim3(2), dim3(1024), 0, stream>>>(cscores, cboxes, out);
}

// Round 3
// 8248.417 us; speedup vs baseline: 1.5092x; 1.0812x over previous
//
#include <hip/hip_runtime.h>
#include <math.h>

// ---------------- problem constants ----------------
#define ATOT 261888          // sum over levels of H*W*3
#define MCAND 21840          // 6000+6000+6000+3072+768 candidates per image
#define POSTK 1000
#define CMB (2*ATOT*5)       // combined output floats = 2618880
#define KB_OFF CMB           // keep_boxes offset in d_out
#define KS_OFF (CMB+8000)    // keep_scores
#define KV_OFF (CMB+10000)   // valid
#define SCALE_CLAMP 4.135166556742356f
#define RCAP 4096

typedef unsigned long long u64;

// ---------------- ws layout (float units) ----------------
#define WS_T   0
#define WS_SC  (256*65536)            // 16777216  (t buffer: one image, largest level)
#define WS_CB  (WS_SC + 2*ATOT)       // scores: 2*261888
#define WS_CS  (WS_CB + 2*MCAND*4)    // cand boxes
#define WS_CTL (WS_CS + 2*MCAND)      // cand scores -> then ctl (u32)

// ctl indices (u32)
#define C_PRE 0
#define C_KCUR 6
#define C_CNT 12
#define C_TIE 18
#define N_THRPREV 24
#define N_KEPT 26
#define N_DONE 28
#define N_SCNT 30
#define N_LAST 32
#define C_GH 40
#define C_TIEIDX (C_GH + 6*256)
#define CTL_SIZE (C_TIEIDX + 6*1024)
#define WS_WP  (WS_CTL + CTL_SIZE)    // prepped conv weights: 589824 floats

// ---- NMS scratch inside the (dead-by-then) t buffer, float offsets from WS_T ----
#define NS_KEY  0                       // u64[2][4096]          -> 16384 floats
#define NS_BOX  16384                   // f32[2][4096*4]        -> 32768
#define NS_AREA 49152                   // f32[2][4096]          -> 8192
#define NS_DIAG 57344                   // u64[2][64][64]        -> 16384
#define NS_PSUP 73728                   // u64[2][64]            -> 256
#define NS_KBOX 73984                   // f32[2][1024*5]        -> 10240
#define NS_MASK 84224                   // u64[2][4096][64]      -> 1048576

__device__ const int LW[5]    = {256,128,64,32,16};
__device__ const int LM[5]    = {196608,49152,12288,3072,768};
__device__ const int LBASE[5] = {0,196608,245760,258048,261120};
__device__ const int LSTR[5]  = {4,8,16,32,64};
__device__ const int LSZ[5]   = {32,64,128,256,512};
__device__ const int CBASE[5] = {0,6000,12000,18000,21072};

__device__ inline unsigned fkey(float f) {
  unsigned u = __float_as_uint(f);
  return u ^ (unsigned)(((int)u >> 31) | 0x80000000);
}
__device__ inline float unfkey(unsigned k) {
  unsigned u = (k & 0x80000000u) ? (k ^ 0x80000000u) : ~k;
  return __uint_as_float(u);
}
__device__ inline int lvl_of(int idx) {
  return idx < 6000 ? 0 : idx < 12000 ? 1 : idx < 18000 ? 2 : idx < 21072 ? 3 : 4;
}
__device__ inline float iou_f(float ax1,float ay1,float ax2,float ay2,float aar,
                              float bx1,float by1,float bx2,float by2,float bar) {
  float ix1 = fmaxf(ax1,bx1), iy1 = fmaxf(ay1,by1);
  float ix2 = fminf(ax2,bx2), iy2 = fminf(ay2,by2);
  float inter = fmaxf(ix2-ix1,0.f) * fmaxf(iy2-iy1,0.f);
  return inter / (aar + bar - inter + 1e-9f);
}

// ---------------- weight prep: wgt[oc][ci][kk] -> wp[(ci*9+kk)][oc] ----------------
__global__ __launch_bounds__(256) void wprep_kernel(const float* __restrict__ wgt,
                                                    float* __restrict__ wp) {
  int o = blockIdx.x*256 + threadIdx.x;
  if (o >= 2304*256) return;
  int ko = o & 255; int rk = o >> 8;
  int ci = rk / 9;  int kk = rk - ci*9;
  wp[o] = wgt[(ko*256 + ci)*9 + kk];
}

// ---------------- conv3x3 + bias + relu (unchanged from R2) ----------------
#define CHK 8
__global__ __launch_bounds__(256,4) void conv3x3_relu(
    const float* __restrict__ in, const float* __restrict__ wp,
    const float* __restrict__ bias, float* __restrict__ outp, int H, int W) {
  const int tid = threadIdx.x;
  const int x0 = blockIdx.x * 16;
  const int y0 = blockIdx.y * 16;
  const int koB = blockIdx.z * 64;
  const int HW = H * W;
  const int oc_g = tid >> 5;
  const int pg   = tid & 31;
  const int row  = pg >> 1;
  const int col0 = (pg & 1) << 3;
  __shared__ float inS[CHK][18][20];
  __shared__ float wS[CHK*9][64];
  float acc[8][8] = {};
  for (int c0 = 0; c0 < 256; c0 += CHK) {
    for (int i = tid; i < CHK*18*18; i += 256) {
      int ci = i / 324; int r = i - ci*324; int iy = r / 18; int ix = r - iy*18;
      int gy = y0 + iy - 1, gx = x0 + ix - 1;
      float v = 0.f;
      if (gy >= 0 && gy < H && gx >= 0 && gx < W) v = in[(c0+ci)*HW + gy*W + gx];
      inS[ci][iy][ix] = v;
    }
    for (int i = tid; i < CHK*9*16; i += 256) {
      int rkk = i >> 4; int c4 = (i & 15) << 2;
      *(float4*)&wS[rkk][c4] = *(const float4*)&wp[(c0*9 + rkk)*256 + koB + c4];
    }
    __syncthreads();
    #pragma unroll
    for (int ci = 0; ci < CHK; ++ci) {
      #pragma unroll
      for (int kh = 0; kh < 3; ++kh) {
        float iv[10];
        float4 t0 = *(const float4*)&inS[ci][row+kh][col0];
        float4 t1 = *(const float4*)&inS[ci][row+kh][col0+4];
        float2 t2 = *(const float2*)&inS[ci][row+kh][col0+8];
        iv[0]=t0.x; iv[1]=t0.y; iv[2]=t0.z; iv[3]=t0.w;
        iv[4]=t1.x; iv[5]=t1.y; iv[6]=t1.z; iv[7]=t1.w;
        iv[8]=t2.x; iv[9]=t2.y;
        #pragma unroll
        for (int kw = 0; kw < 3; ++kw) {
          const int rr = ci*9 + kh*3 + kw;
          float4 w0 = *(const float4*)&wS[rr][oc_g*8];
          float4 w1 = *(const float4*)&wS[rr][oc_g*8+4];
          float wv[8] = {w0.x,w0.y,w0.z,w0.w,w1.x,w1.y,w1.z,w1.w};
          #pragma unroll
          for (int k = 0; k < 8; ++k)
            #pragma unroll
            for (int j = 0; j < 8; ++j)
              acc[k][j] += wv[k] * iv[kw+j];
        }
      }
    }
    __syncthreads();
  }
  const int oy = y0 + row, ox = x0 + col0;
  #pragma unroll
  for (int k = 0; k < 8; ++k) {
    int oc = koB + oc_g*8 + k;
    float bb = bias[oc];
    float4 v0, v1;
    v0.x = fmaxf(acc[k][0]+bb, 0.f); v0.y = fmaxf(acc[k][1]+bb, 0.f);
    v0.z = fmaxf(acc[k][2]+bb, 0.f); v0.w = fmaxf(acc[k][3]+bb, 0.f);
    v1.x = fmaxf(acc[k][4]+bb, 0.f); v1.y = fmaxf(acc[k][5]+bb, 0.f);
    v1.z = fmaxf(acc[k][6]+bb, 0.f); v1.w = fmaxf(acc[k][7]+bb, 0.f);
    *(float4*)&outp[oc*HW + oy*W + ox]     = v0;
    *(float4*)&outp[oc*HW + oy*W + ox + 4] = v1;
  }
}

// ---------------- 1x1 heads ----------------
__global__ __launch_bounds__(256) void heads1x1(
    const float* __restrict__ t, const float* __restrict__ ow, const float* __restrict__ ob,
    const float* __restrict__ dw, const float* __restrict__ db,
    float* __restrict__ comb, float* __restrict__ scores, int HW, int lbase, int n) {
  __shared__ float wS[15][256];
  const int tid = threadIdx.x;
  for (int i = tid; i < 3*256; i += 256) wS[i>>8][i&255] = ow[i];
  for (int i = tid; i < 12*256; i += 256) wS[3+(i>>8)][i&255] = dw[i];
  __syncthreads();
  int p0 = (blockIdx.x*256 + tid) * 4;
  if (p0 >= HW) return;
  float acc[15][4] = {};
  for (int c = 0; c < 256; ++c) {
    float4 v = *(const float4*)&t[c*HW + p0];
    float vv[4] = {v.x, v.y, v.z, v.w};
    #pragma unroll
    for (int k = 0; k < 15; ++k) {
      float w = wS[k][c];
      #pragma unroll
      for (int j = 0; j < 4; ++j) acc[k][j] += w * vv[j];
    }
  }
  float obv[3]; for (int i2 = 0; i2 < 3; ++i2) obv[i2] = ob[i2];
  float dbv[12]; for (int i2 = 0; i2 < 12; ++i2) dbv[i2] = db[i2];
  for (int j = 0; j < 4; ++j) {
    int pos = p0 + j;
    long base = (long)n*ATOT + lbase + (long)pos*3;
    #pragma unroll
    for (int a = 0; a < 3; ++a) {
      float lg = acc[a][j] + obv[a];
      comb[(base+a)*5] = lg;
      scores[(long)n*ATOT + lbase + pos*3 + a] = lg;
      #pragma unroll
      for (int q = 0; q < 4; ++q)
        comb[(base+a)*5 + 1 + q] = acc[3 + a*4 + q][j] + dbv[a*4+q];
    }
  }
}

// ---------------- decode ----------------
__device__ void decode_store(int n, int lvl, int idx, int slot,
                             const float* comb, float* cboxes, float* cscores) {
  int W = LW[lvl];
  int a = idx % 3; int p = idx / 3;
  int wx = p % W, hy = p / W;
  double r = (a == 0) ? 0.5 : (a == 1) ? 1.0 : 2.0;
  double sz = (double)LSZ[lvl];
  double wsd = sqrt(sz*sz/r);
  double hsd = wsd * r;
  double cxd = (double)(wx * LSTR[lvl]);
  double cyd = (double)(hy * LSTR[lvl]);
  float ax1 = (float)(cxd - 0.5*wsd), ay1 = (float)(cyd - 0.5*hsd);
  float ax2 = (float)(cxd + 0.5*wsd), ay2 = (float)(cyd + 0.5*hsd);
  float aw = ax2 - ax1, ah = ay2 - ay1;
  float acx = ax1 + 0.5f*aw, acy = ay1 + 0.5f*ah;
  long g = (long)n*ATOT + LBASE[lvl] + idx;
  const float* cm = comb + g*5;
  float sc = cm[0];
  float dx = cm[1], dy = cm[2], dwv = cm[3], dhv = cm[4];
  dwv = fminf(dwv, SCALE_CLAMP); dhv = fminf(dhv, SCALE_CLAMP);
  float pcx = __fadd_rn(__fmul_rn(dx, aw), acx);
  float pcy = __fadd_rn(__fmul_rn(dy, ah), acy);
  float pw = __fmul_rn(expf(dwv), aw);
  float ph = __fmul_rn(expf(dhv), ah);
  float x1 = __fsub_rn(pcx, 0.5f*pw), y1 = __fsub_rn(pcy, 0.5f*ph);
  float x2 = __fadd_rn(pcx, 0.5f*pw), y2 = __fadd_rn(pcy, 0.5f*ph);
  x1 = fminf(fmaxf(x1, 0.f), 1024.f);
  y1 = fminf(fmaxf(y1, 0.f), 1024.f);
  x2 = fminf(fmaxf(x2, 0.f), 1024.f);
  y2 = fminf(fmaxf(y2, 0.f), 1024.f);
  float* cbp = cboxes + ((long)n*MCAND + slot)*4;
  cbp[0]=x1; cbp[1]=y1; cbp[2]=x2; cbp[3]=y2;
  cscores[(long)n*MCAND + slot] = sc;
}

// ---------------- top-k kernels ----------------
__global__ void init_ctl(unsigned* ctl) {
  for (int i = threadIdx.x; i < CTL_SIZE; i += 256) ctl[i] = 0;
  __syncthreads();
  if (threadIdx.x < 6) ctl[C_KCUR + threadIdx.x] = 6000;
  if (threadIdx.x < 2) ctl[N_THRPREV + threadIdx.x] = 0xFFFFFFFFu;
}

__global__ __launch_bounds__(256) void tk_hist(const float* __restrict__ scores,
                                               unsigned* ctl, int pass) {
  int t = blockIdx.y; int lvl = t >> 1, n = t & 1;
  int M = LM[lvl]; long base = (long)n*ATOT + LBASE[lvl];
  __shared__ unsigned h[256];
  h[threadIdx.x] = 0;
  __syncthreads();
  unsigned prefix = ctl[C_PRE + t];
  int shift = 24 - 8*pass;
  for (int i = blockIdx.x*256 + threadIdx.x; i < M; i += gridDim.x*256) {
    unsigned key = fkey(scores[base + i]);
    if (pass == 0 || (key >> (shift+8)) == prefix)
      atomicAdd(&h[(key >> shift) & 255], 1u);
  }
  __syncthreads();
  if (h[threadIdx.x]) atomicAdd(&ctl[C_GH + t*256 + threadIdx.x], h[threadIdx.x]);
}

__global__ __launch_bounds__(256) void tk_pick(unsigned* ctl) {
  int t = blockIdx.x;
  if (threadIdx.x == 0) {
    unsigned kcur = ctl[C_KCUR + t];
    int digit = 0;
    for (int d = 255; d >= 0; --d) {
      unsigned c = ctl[C_GH + t*256 + d];
      if (kcur <= c) { digit = d; break; }
      kcur -= c;
    }
    ctl[C_KCUR + t] = kcur;
    ctl[C_PRE + t] = (ctl[C_PRE + t] << 8) | (unsigned)digit;
  }
  __syncthreads();
  ctl[C_GH + t*256 + threadIdx.x] = 0;
}

__global__ __launch_bounds__(256) void tk_compact(const float* __restrict__ scores,
    const float* __restrict__ comb, unsigned* ctl, float* cboxes, float* cscores) {
  int t = blockIdx.y; int lvl = t >> 1, n = t & 1;
  int M = LM[lvl]; long base = (long)n*ATOT + LBASE[lvl];
  unsigned thr = ctl[C_PRE + t];
  for (int i = blockIdx.x*256 + threadIdx.x; i < M; i += gridDim.x*256) {
    unsigned key = fkey(scores[base + i]);
    if (key > thr) {
      unsigned p = atomicAdd(&ctl[C_CNT + t], 1u);
      if (p < 6000u) decode_store(n, lvl, i, CBASE[lvl] + (int)p, comb, cboxes, cscores);
    } else if (key == thr) {
      unsigned p = atomicAdd(&ctl[C_TIE + t], 1u);
      if (p < 1024u) ctl[C_TIEIDX + t*1024 + p] = (unsigned)i;
    }
  }
}

__global__ void tk_finalize(const float* __restrict__ comb, unsigned* ctl,
                            float* cboxes, float* cscores) {
  int t = blockIdx.x; int lvl = t >> 1, n = t & 1;
  if (threadIdx.x != 0) return;
  int cnt = (int)ctl[C_CNT + t]; if (cnt > 6000) cnt = 6000;
  int need = 6000 - cnt;
  int tc = (int)ctl[C_TIE + t]; if (tc > 1024) tc = 1024;
  unsigned* tb = &ctl[C_TIEIDX + t*1024];
  for (int s = 0; s < need; ++s) {
    unsigned mn = 0xFFFFFFFFu; int mi = -1;
    for (int q = 0; q < tc; ++q) { if (tb[q] < mn) { mn = tb[q]; mi = q; } }
    int slot = CBASE[lvl] + cnt + s;
    if (mi >= 0) {
      tb[mi] = 0xFFFFFFFFu;
      decode_store(n, lvl, (int)mn, slot, comb, cboxes, cscores);
    } else {
      float* cbp = cboxes + ((long)n*MCAND + slot)*4;
      cbp[0]=cbp[1]=cbp[2]=cbp[3]=0.f;
      cscores[(long)n*MCAND + slot] = -3.0e38f;
    }
  }
}

__global__ void decode34(const float* __restrict__ comb, float* cboxes, float* cscores) {
  int n = blockIdx.y;
  int e = blockIdx.x*256 + threadIdx.x;
  if (e >= 3840) return;
  if (e < 3072) decode_store(n, 3, e, 18000 + e, comb, cboxes, cscores);
  else          decode_store(n, 4, e - 3072, 21072 + (e - 3072), comb, cboxes, cscores);
}

// =============== NMS: matrix pipeline ===============

// K1: radix-select top-RCAP below thrPrev, bitonic sort desc, decode offset boxes.
__global__ __launch_bounds__(1024) void nms_select(
    const float* __restrict__ cscores, const float* __restrict__ cboxes,
    float* __restrict__ wt, unsigned* ctl) {
  const int n = blockIdx.x;
  if (ctl[N_DONE + n]) return;
  const int tid = threadIdx.x;
  const float* sc = cscores + (long)n*MCAND;
  const float* cb = cboxes + (long)n*MCAND*4;
  u64* skeyG   = ((u64*)(wt + NS_KEY)) + n*RCAP;
  float* boxO  = wt + NS_BOX + n*RCAP*4;
  float* areaG = wt + NS_AREA + n*RCAP;
  __shared__ u64 skey[RCAP];
  __shared__ unsigned hist[256];
  __shared__ unsigned sS[8];
  unsigned thrPrev = ctl[N_THRPREV + n];
  unsigned prefix = 0, kcur = RCAP;
  for (int pass = 0; pass < 4; ++pass) {
    if (tid < 256) hist[tid] = 0;
    __syncthreads();
    int shift = 24 - 8*pass;
    for (int i = tid; i < MCAND; i += 1024) {
      unsigned key = fkey(sc[i]);
      if (key < thrPrev && (pass == 0 || (key >> (shift+8)) == prefix))
        atomicAdd(&hist[(key >> shift) & 255], 1u);
    }
    __syncthreads();
    if (tid == 0) {
      if (pass == 0) { unsigned s = 0; for (int d = 0; d < 256; ++d) s += hist[d]; sS[2] = s; }
      if (sS[2] > RCAP) {
        unsigned kc = kcur; int digit = 0;
        for (int d = 255; d >= 0; --d) {
          unsigned c = hist[d];
          if (kc <= c) { digit = d; break; }
          kc -= c;
        }
        kcur = kc;
        prefix = (prefix << 8) | (unsigned)digit;
        sS[4] = prefix;
      } else sS[4] = 0;
    }
    __syncthreads();
    prefix = sS[4];
    if (sS[2] <= RCAP) break;
  }
  unsigned thr = (sS[2] <= RCAP) ? 0u : sS[4];
  if (tid == 0) sS[0] = 0;
  for (int i = tid; i < RCAP; i += 1024) skey[i] = 0;
  __syncthreads();
  for (int i = tid; i < MCAND; i += 1024) {
    unsigned key = fkey(sc[i]);
    if (key < thrPrev && key >= thr) {
      unsigned p = atomicAdd(&sS[0], 1u);
      if (p < RCAP) skey[p] = ((u64)key << 32) | (unsigned)(~i);
    }
  }
  __syncthreads();
  unsigned scnt = sS[0] > RCAP ? RCAP : sS[0];
  // bitonic sort desc
  for (int kk = 2; kk <= RCAP; kk <<= 1) {
    for (int jj = kk >> 1; jj > 0; jj >>= 1) {
      for (int i = tid; i < RCAP; i += 1024) {
        int ixj = i ^ jj;
        if (ixj > i) {
          u64 a = skey[i], b = skey[ixj];
          bool up = ((i & kk) == 0);
          if ((a < b) == up) { skey[i] = b; skey[ixj] = a; }
        }
      }
      __syncthreads();
    }
  }
  // write sorted + decoded offset boxes
  for (int s = tid; s < RCAP; s += 1024) {
    u64 v = skey[s];
    skeyG[s] = v;
    float x1=0.f,y1=0.f,x2=0.f,y2=0.f,ar=0.f;
    if (v) {
      int idx = (int)(~(unsigned)v);
      float off = 2000.f * (float)lvl_of(idx);
      x1 = cb[idx*4+0] + off; y1 = cb[idx*4+1] + off;
      x2 = cb[idx*4+2] + off; y2 = cb[idx*4+3] + off;
      ar = (x2-x1)*(y2-y1);
    }
    boxO[s*4+0]=x1; boxO[s*4+1]=y1; boxO[s*4+2]=x2; boxO[s*4+3]=y2;
    areaG[s]=ar;
  }
  if (tid == 0) {
    ctl[N_SCNT + n] = scnt;
    ctl[N_THRPREV + n] = thr;
    if (thr == 0u) ctl[N_LAST + n] = 1;
    if (scnt == 0) ctl[N_DONE + n] = 1;
  }
}

// K2: suppression-mask matrix + pre-suppression vs previously-kept. grid (64, 2), block 256.
__global__ __launch_bounds__(256) void nms_matrix(const float* __restrict__ wt_c,
                                                  float* __restrict__ wt, unsigned* ctl) {
  const int n = blockIdx.y;
  if (ctl[N_DONE + n]) return;
  const int bx = blockIdx.x;
  const int i0 = bx * 64;
  const int tid = threadIdx.x;
  const int wv = tid >> 6;
  const int lane = tid & 63;
  const float* boxO  = wt_c + NS_BOX + n*RCAP*4;
  const float* areaG = wt_c + NS_AREA + n*RCAP;
  const float* kbox  = wt_c + NS_KBOX + n*1024*5;
  u64* mask  = ((u64*)(wt + NS_MASK)) + (long)n*RCAP*64;
  u64* diagA = ((u64*)(wt + NS_DIAG)) + n*64*64;
  u64* psupW = ((u64*)(wt + NS_PSUP)) + n*64;
  int kt0 = (int)ctl[N_KEPT + n];
  __shared__ float rb[64][5];
  __shared__ unsigned psw[2];
  if (tid < 2) psw[tid] = 0;
  if (tid < 64) {
    rb[tid][0]=boxO[(i0+tid)*4+0]; rb[tid][1]=boxO[(i0+tid)*4+1];
    rb[tid][2]=boxO[(i0+tid)*4+2]; rb[tid][3]=boxO[(i0+tid)*4+3];
    rb[tid][4]=areaG[i0+tid];
  }
  __syncthreads();
  if (kt0 > 0) {
    for (int rr = 0; rr < 16; ++rr) {
      int il = wv*16 + rr;
      float rx1=rb[il][0], ry1=rb[il][1], rx2=rb[il][2], ry2=rb[il][3], rar=rb[il][4];
      bool s = false;
      for (int k = lane; k < kt0; k += 64) {
        float iou = iou_f(rx1,ry1,rx2,ry2,rar,
                          kbox[k*5+0],kbox[k*5+1],kbox[k*5+2],kbox[k*5+3],kbox[k*5+4]);
        s |= (iou > 0.7f);
      }
      u64 bal = __ballot(s);
      if (lane == 0 && bal) atomicOr(&psw[il>>5], 1u << (il & 31));
    }
  }
  __syncthreads();
  if (tid == 0) psupW[bx] = ((u64)psw[1] << 32) | psw[0];
  // mask words
  for (int w = 0; w < 64; ++w) {
    int cidx = w*64 + lane;
    float cx1=boxO[cidx*4+0], cy1=boxO[cidx*4+1], cx2=boxO[cidx*4+2], cy2=boxO[cidx*4+3];
    float car=areaG[cidx];
    #pragma unroll 4
    for (int rr = 0; rr < 16; ++rr) {
      int il = wv*16 + rr;
      int i = i0 + il;
      float iou = iou_f(rb[il][0],rb[il][1],rb[il][2],rb[il][3],rb[il][4],
                        cx1,cy1,cx2,cy2,car);
      bool bit = (iou > 0.7f) && (cidx > i);
      u64 m = __ballot(bit);
      if (lane == 0) {
        mask[(long)i*64 + w] = m;
        if (w == bx) diagA[bx*64 + il] = m;
      }
    }
  }
}

// K3: serial greedy scan over bitmasks. grid 2, block 64 (1 wave).
__global__ __launch_bounds__(64) void nms_scan(
    const float* __restrict__ cscores, const float* __restrict__ cboxes,
    float* __restrict__ wt, unsigned* ctl, float* __restrict__ dout) {
  const int n = blockIdx.x;
  if (ctl[N_DONE + n]) return;
  const int lane = threadIdx.x;
  const float* cb = cboxes + (long)n*MCAND*4;
  u64* skeyG = ((u64*)(wt + NS_KEY)) + n*RCAP;
  const float* boxO  = wt + NS_BOX + n*RCAP*4;
  const float* areaG = wt + NS_AREA + n*RCAP;
  u64* mask  = ((u64*)(wt + NS_MASK)) + (long)n*RCAP*64;
  u64* diagA = ((u64*)(wt + NS_DIAG)) + n*64*64;
  u64* psupW = ((u64*)(wt + NS_PSUP)) + n*64;
  float* kbox = wt + NS_KBOX + n*1024*5;
  float* keepB = dout + KB_OFF + (long)n*4*POSTK;
  float* keepS = dout + KS_OFF + (long)n*POSTK;
  float* keepV = dout + KV_OFF + (long)n*POSTK;
  int scnt = (int)ctl[N_SCNT + n];
  int kt = (int)ctl[N_KEPT + n];
  __shared__ u64 alive[64];
  {
    int rem = scnt - lane*64;
    u64 a = rem >= 64 ? ~0ull : (rem > 0 ? ((1ull << rem) - 1ull) : 0ull);
    alive[lane] = a & ~psupW[lane];
  }
  __syncthreads();
  for (int c = 0; c < 64 && kt < POSTK; ++c) {
    u64 w64 = alive[c];
    if (!w64) continue;
    u64 diag = diagA[c*64 + lane];
    u64 kb = 0;
    while (w64) {
      int b = __ffsll(w64) - 1;
      kb |= (1ull << b);
      w64 &= ~(1ull << b);
      u64 sup = __shfl(diag, b);
      w64 &= ~sup;
      if (++kt >= POSTK) break;
    }
    alive[c] = 0;
    // append kept (lane-parallel)
    if ((kb >> lane) & 1) {
      int base = kt - (int)__popcll(kb);
      int pos = base + (int)__popcll(kb & ((1ull << lane) - 1ull));
      int s = c*64 + lane;
      u64 v = skeyG[s];
      int idx = (int)(~(unsigned)v);
      keepB[pos*4+0]=cb[idx*4+0]; keepB[pos*4+1]=cb[idx*4+1];
      keepB[pos*4+2]=cb[idx*4+2]; keepB[pos*4+3]=cb[idx*4+3];
      keepS[pos] = unfkey((unsigned)(v >> 32));
      keepV[pos] = 1.f;
      kbox[pos*5+0]=boxO[s*4+0]; kbox[pos*5+1]=boxO[s*4+1];
      kbox[pos*5+2]=boxO[s*4+2]; kbox[pos*5+3]=boxO[s*4+3];
      kbox[pos*5+4]=areaG[s];
    }
    __syncthreads();
    // cross-chunk suppression: lane w clears its word from kept rows
    if (kb && lane > c && alive[lane]) {
      u64 acc = 0, m = kb;
      while (m) {
        int b = __ffsll(m) - 1; m &= m - 1;
        acc |= mask[(long)(c*64 + b)*64 + lane];
      }
      if (acc) alive[lane] &= ~acc;
    }
    __syncthreads();
  }
  if (lane == 0) {
    ctl[N_KEPT + n] = (unsigned)kt;
    if (kt >= POSTK || ctl[N_LAST + n]) ctl[N_DONE + n] = 1;
  }
}

// K4: fill remaining slots with reference's exhaustion value (candidate slot 0 = best level-0).
__device__ inline u64 shfl_down_u64d(u64 v, int o) {
  unsigned hi = __shfl_down((unsigned)(v >> 32), o);
  unsigned lo = __shfl_down((unsigned)v, o);
  return ((u64)hi << 32) | lo;
}
__global__ __launch_bounds__(1024) void nms_fill(
    const float* __restrict__ cscores, const float* __restrict__ cboxes,
    unsigned* ctl, float* __restrict__ dout) {
  const int n = blockIdx.x;
  const int tid = threadIdx.x;
  const int lane = tid & 63;
  const int wid = tid >> 6;
  const float* sc = cscores + (long)n*MCAND;
  const float* cb = cboxes + (long)n*MCAND*4;
  float* keepB = dout + KB_OFF + (long)n*4*POSTK;
  float* keepS = dout + KS_OFF + (long)n*POSTK;
  float* keepV = dout + KV_OFF + (long)n*POSTK;
  __shared__ u64 wred[16];
  __shared__ u64 sBest;
  u64 best = 0;
  for (int i = tid; i < 6000; i += 1024) {
    u64 v = ((u64)fkey(sc[i]) << 32) | (unsigned)(~i);
    if (v > best) best = v;
  }
  for (int o = 32; o > 0; o >>= 1) {
    u64 ov = shfl_down_u64d(best, o);
    if (ov > best) best = ov;
  }
  if (lane == 0) wred[wid] = best;
  __syncthreads();
  if (tid == 0) {
    u64 b = 0;
    for (int i = 0; i < 16; ++i) if (wred[i] > b) b = wred[i];
    sBest = b;
  }
  __syncthreads();
  int kt = (int)ctl[N_KEPT + n];
  int bidx = (int)(~(unsigned)sBest);
  float b0 = cb[bidx*4+0], b1 = cb[bidx*4+1], b2 = cb[bidx*4+2], b3 = cb[bidx*4+3];
  float bsc = sc[bidx];
  for (int s2 = kt + tid; s2 < POSTK; s2 += 1024) {
    keepB[s2*4+0]=b0; keepB[s2*4+1]=b1; keepB[s2*4+2]=b2; keepB[s2*4+3]=b3;
    keepS[s2] = bsc; keepV[s2] = 0.f;
  }
}

// ---------------- launcher ----------------
extern "C" void kernel_launch(void* const* d_in, const int* in_sizes, int n_in,
                              void* d_out, int out_size, void* d_ws, size_t ws_size,
                              hipStream_t stream) {
  const float* feats[5];
  for (int i = 0; i < 5; ++i) feats[i] = (const float*)d_in[i];
  const float* conv_w  = (const float*)d_in[5];
  const float* conv_b  = (const float*)d_in[6];
  const float* obj_w   = (const float*)d_in[7];
  const float* obj_b   = (const float*)d_in[8];
  const float* delta_w = (const float*)d_in[9];
  const float* delta_b = (const float*)d_in[10];
  float* out = (float*)d_out;
  float* ws = (float*)d_ws;
  float* t       = ws + WS_T;
  float* scores  = ws + WS_SC;
  float* cboxes  = ws + WS_CB;
  float* cscores = ws + WS_CS;
  unsigned* ctl  = (unsigned*)(ws + WS_CTL);
  float* wp      = ws + WS_WP;

  static const int LWh[5]    = {256,128,64,32,16};
  static const int LBASEh[5] = {0,196608,245760,258048,261120};

  wprep_kernel<<<dim3(2304), dim3(256), 0, stream>>>(conv_w, wp);
  init_ctl<<<dim3(1), dim3(256), 0, stream>>>(ctl);
  for (int n = 0; n < 2; ++n) {
    for (int lvl = 0; lvl < 5; ++lvl) {
      int H = LWh[lvl], W = LWh[lvl], HW = H*W;
      conv3x3_relu<<<dim3(W/16, H/16, 4), dim3(256), 0, stream>>>(
          feats[lvl] + (long)n*256*HW, wp, conv_b, t, H, W);
      int hb = (HW + 1023) / 1024;
      heads1x1<<<dim3(hb), dim3(256), 0, stream>>>(
          t, obj_w, obj_b, delta_w, delta_b, out, scores, HW, LBASEh[lvl], n);
    }
  }
  for (int p = 0; p < 4; ++p) {
    tk_hist<<<dim3(48,6), dim3(256), 0, stream>>>(scores, ctl, p);
    tk_pick<<<dim3(6), dim3(256), 0, stream>>>(ctl);
  }
  tk_compact<<<dim3(48,6), dim3(256), 0, stream>>>(scores, out, ctl, cboxes, cscores);
  tk_finalize<<<dim3(6), dim3(64), 0, stream>>>(out, ctl, cboxes, cscores);
  decode34<<<dim3(15,2), dim3(256), 0, stream>>>(out, cboxes, cscores);
  // NMS: 6 fixed batches (early-exit via done flag), then fill.
  for (int b = 0; b < 6; ++b) {
    nms_select<<<dim3(2), dim3(1024), 0, stream>>>(cscores, cboxes, t, ctl);
    nms_matrix<<<dim3(64,2), dim3(256), 0, stream>>>(t, t, ctl);
    nms_scan<<<dim3(2), dim3(64), 0, stream>>>(cscores, cboxes, t, ctl, out);
  }
  nms_fill<<<dim3(2), dim3(1024), 0, stream>>>(cscores, cboxes, ctl, out);
}

// Round 4
// 4393.818 us; speedup vs baseline: 2.8332x; 1.8773x over previous
//
#include <hip/hip_runtime.h>
#include <math.h>

// ---------------- problem constants ----------------
#define ATOT 261888          // sum over levels of H*W*3
#define MCAND 21840          // 6000+6000+6000+3072+768 candidates per image
#define POSTK 1000
#define CMB (2*ATOT*5)       // combined output floats = 2618880
#define KB_OFF CMB           // keep_boxes offset in d_out
#define KS_OFF (CMB+8000)    // keep_scores
#define KV_OFF (CMB+10000)   // valid
#define SCALE_CLAMP 4.135166556742356f
#define RCAP 4096

typedef unsigned long long u64;

// ---------------- fallback (small-ws) layout, float units ----------------
#define WS_T   0
#define WS_SC  (256*65536)
#define WS_CB  (WS_SC + 2*ATOT)
#define WS_CS  (WS_CB + 2*MCAND*4)
#define WS_CTL (WS_CS + 2*MCAND)

// ctl indices (u32)
#define C_PRE 0
#define C_KCUR 6
#define C_CNT 12
#define C_TIE 18
#define N_THRPREV 24
#define N_KEPT 26
#define N_DONE 28
#define N_SCNT 30
#define N_LAST 32
#define C_GH 40
#define C_TIEIDX (C_GH + 6*256)
#define CTL_SIZE (C_TIEIDX + 6*1024)
#define WS_WP  (WS_CTL + CTL_SIZE)

// ---------------- fused (big-ws) layout, float units ----------------
#define FT_T   0
#define FT_TSZ 22347776                 // 256 * 87296 (all levels, one image)
#define FT_SC  22347776
#define FT_CB  (FT_SC + 2*ATOT)         // 22871552
#define FT_CS  (FT_CB + 2*MCAND*4)      // 23046272
#define FT_CTL (FT_CS + 2*MCAND)        // 23089952
#define FT_WP  (FT_CTL + CTL_SIZE)      // 23097672
#define FT_END (FT_WP + 589824)         // 23687496 floats = 94,749,984 B

// ---- NMS scratch inside the (dead-by-then) t buffer ----
#define NS_KEY  0
#define NS_BOX  16384
#define NS_AREA 49152
#define NS_DIAG 57344
#define NS_PSUP 73728
#define NS_KBOX 73984
#define NS_MASK 84224                   // end 1,132,800 floats

__device__ const int LW[5]    = {256,128,64,32,16};
__device__ const int LM[5]    = {196608,49152,12288,3072,768};
__device__ const int LBASE[5] = {0,196608,245760,258048,261120};
__device__ const int LSTR[5]  = {4,8,16,32,64};
__device__ const int LSZ[5]   = {32,64,128,256,512};
__device__ const int CBASE[5] = {0,6000,12000,18000,21072};
__device__ const int TOFF[5]  = {0,16777216,20971520,22020096,22282240}; // 256*cumHW

__device__ inline unsigned fkey(float f) {
  unsigned u = __float_as_uint(f);
  return u ^ (unsigned)(((int)u >> 31) | 0x80000000);
}
__device__ inline float unfkey(unsigned k) {
  unsigned u = (k & 0x80000000u) ? (k ^ 0x80000000u) : ~k;
  return __uint_as_float(u);
}
__device__ inline int lvl_of(int idx) {
  return idx < 6000 ? 0 : idx < 12000 ? 1 : idx < 18000 ? 2 : idx < 21072 ? 3 : 4;
}
__device__ inline float iou_f(float ax1,float ay1,float ax2,float ay2,float aar,
                              float bx1,float by1,float bx2,float by2,float bar) {
  float ix1 = fmaxf(ax1,bx1), iy1 = fmaxf(ay1,by1);
  float ix2 = fminf(ax2,bx2), iy2 = fminf(ay2,by2);
  float inter = fmaxf(ix2-ix1,0.f) * fmaxf(iy2-iy1,0.f);
  return inter / (aar + bar - inter + 1e-9f);
}

// ---------------- weight prep: wgt[oc][ci][kk] -> wp[(ci*9+kk)][oc] ----------------
__global__ __launch_bounds__(256) void wprep_kernel(const float* __restrict__ wgt,
                                                    float* __restrict__ wp) {
  int o = blockIdx.x*256 + threadIdx.x;
  if (o >= 2304*256) return;
  int ko = o & 255; int rk = o >> 8;
  int ci = rk / 9;  int kk = rk - ci*9;
  wp[o] = wgt[(ko*256 + ci)*9 + kk];
}

// ---------------- conv core (shared by fused & fallback) ----------------
#define CHK 8
__device__ __forceinline__ void conv_tile_body(
    const float* __restrict__ in, const float* __restrict__ wp,
    const float* __restrict__ bias, float* __restrict__ outp,
    int H, int W, int x0, int y0, int koB) {
  const int tid = threadIdx.x;
  const int HW = H * W;
  const int oc_g = tid >> 5;
  const int pg   = tid & 31;
  const int row  = pg >> 1;
  const int col0 = (pg & 1) << 3;
  __shared__ float inS[CHK][18][20];
  __shared__ float wS[CHK*9][64];
  float acc[8][8] = {};
  for (int c0 = 0; c0 < 256; c0 += CHK) {
    for (int i = tid; i < CHK*18*18; i += 256) {
      int ci = i / 324; int r = i - ci*324; int iy = r / 18; int ix = r - iy*18;
      int gy = y0 + iy - 1, gx = x0 + ix - 1;
      float v = 0.f;
      if (gy >= 0 && gy < H && gx >= 0 && gx < W) v = in[(c0+ci)*HW + gy*W + gx];
      inS[ci][iy][ix] = v;
    }
    for (int i = tid; i < CHK*9*16; i += 256) {
      int rkk = i >> 4; int c4 = (i & 15) << 2;
      *(float4*)&wS[rkk][c4] = *(const float4*)&wp[(c0*9 + rkk)*256 + koB + c4];
    }
    __syncthreads();
    #pragma unroll
    for (int ci = 0; ci < CHK; ++ci) {
      #pragma unroll
      for (int kh = 0; kh < 3; ++kh) {
        float iv[10];
        float4 t0 = *(const float4*)&inS[ci][row+kh][col0];
        float4 t1 = *(const float4*)&inS[ci][row+kh][col0+4];
        float2 t2 = *(const float2*)&inS[ci][row+kh][col0+8];
        iv[0]=t0.x; iv[1]=t0.y; iv[2]=t0.z; iv[3]=t0.w;
        iv[4]=t1.x; iv[5]=t1.y; iv[6]=t1.z; iv[7]=t1.w;
        iv[8]=t2.x; iv[9]=t2.y;
        #pragma unroll
        for (int kw = 0; kw < 3; ++kw) {
          const int rr = ci*9 + kh*3 + kw;
          float4 w0 = *(const float4*)&wS[rr][oc_g*8];
          float4 w1 = *(const float4*)&wS[rr][oc_g*8+4];
          float wv[8] = {w0.x,w0.y,w0.z,w0.w,w1.x,w1.y,w1.z,w1.w};
          #pragma unroll
          for (int k = 0; k < 8; ++k)
            #pragma unroll
            for (int j = 0; j < 8; ++j)
              acc[k][j] += wv[k] * iv[kw+j];
        }
      }
    }
    __syncthreads();
  }
  const int oy = y0 + row, ox = x0 + col0;
  #pragma unroll
  for (int k = 0; k < 8; ++k) {
    int oc = koB + oc_g*8 + k;
    float bb = bias[oc];
    float4 v0, v1;
    v0.x = fmaxf(acc[k][0]+bb, 0.f); v0.y = fmaxf(acc[k][1]+bb, 0.f);
    v0.z = fmaxf(acc[k][2]+bb, 0.f); v0.w = fmaxf(acc[k][3]+bb, 0.f);
    v1.x = fmaxf(acc[k][4]+bb, 0.f); v1.y = fmaxf(acc[k][5]+bb, 0.f);
    v1.z = fmaxf(acc[k][6]+bb, 0.f); v1.w = fmaxf(acc[k][7]+bb, 0.f);
    *(float4*)&outp[oc*HW + oy*W + ox]     = v0;
    *(float4*)&outp[oc*HW + oy*W + ox + 4] = v1;
  }
}

// fallback: one level per dispatch
__global__ __launch_bounds__(256,2) void conv3x3_relu(
    const float* __restrict__ in, const float* __restrict__ wp,
    const float* __restrict__ bias, float* __restrict__ outp, int H, int W) {
  conv_tile_body(in, wp, bias, outp, H, W, blockIdx.x*16, blockIdx.y*16, blockIdx.z*64);
}

// fused: all 5 levels of one image in one dispatch. 1364 blocks.
__global__ __launch_bounds__(256,2) void conv_fused(
    const float* __restrict__ f0, const float* __restrict__ f1,
    const float* __restrict__ f2, const float* __restrict__ f3,
    const float* __restrict__ f4, const float* __restrict__ wp,
    const float* __restrict__ bias, float* __restrict__ t, int n) {
  int id = blockIdx.x;
  int lvl, rem;
  if (id < 1024)      { lvl = 0; rem = id; }
  else if (id < 1280) { lvl = 1; rem = id - 1024; }
  else if (id < 1344) { lvl = 2; rem = id - 1280; }
  else if (id < 1360) { lvl = 3; rem = id - 1344; }
  else                { lvl = 4; rem = id - 1360; }
  const int W = LW[lvl];
  const int tw = W >> 4;
  const int ntile = tw * tw;
  int og = rem / ntile; int tile = rem - og*ntile;
  int ty = tile / tw, tx = tile - ty*tw;
  const float* in = (lvl==0?f0:lvl==1?f1:lvl==2?f2:lvl==3?f3:f4) + (long)n*256*W*W;
  conv_tile_body(in, wp, bias, t + TOFF[lvl], W, W, tx*16, ty*16, og*64);
}

// ---------------- 1x1 heads ----------------
__device__ __forceinline__ void heads_body(
    const float* __restrict__ t, const float* __restrict__ ow, const float* __restrict__ ob,
    const float* __restrict__ dw, const float* __restrict__ db,
    float* __restrict__ comb, float* __restrict__ scores,
    int HW, int lbase, int n, int p0) {
  __shared__ float wS[15][256];
  const int tid = threadIdx.x;
  for (int i = tid; i < 3*256; i += 256) wS[i>>8][i&255] = ow[i];
  for (int i = tid; i < 12*256; i += 256) wS[3+(i>>8)][i&255] = dw[i];
  __syncthreads();
  if (p0 >= HW) return;
  float acc[15][4] = {};
  for (int c = 0; c < 256; ++c) {
    float4 v = *(const float4*)&t[c*HW + p0];
    float vv[4] = {v.x, v.y, v.z, v.w};
    #pragma unroll
    for (int k = 0; k < 15; ++k) {
      float w = wS[k][c];
      #pragma unroll
      for (int j = 0; j < 4; ++j) acc[k][j] += w * vv[j];
    }
  }
  float obv[3]; for (int i2 = 0; i2 < 3; ++i2) obv[i2] = ob[i2];
  float dbv[12]; for (int i2 = 0; i2 < 12; ++i2) dbv[i2] = db[i2];
  for (int j = 0; j < 4; ++j) {
    int pos = p0 + j;
    long base = (long)n*ATOT + lbase + (long)pos*3;
    #pragma unroll
    for (int a = 0; a < 3; ++a) {
      float lg = acc[a][j] + obv[a];
      comb[(base+a)*5] = lg;
      scores[(long)n*ATOT + lbase + pos*3 + a] = lg;
      #pragma unroll
      for (int q = 0; q < 4; ++q)
        comb[(base+a)*5 + 1 + q] = acc[3 + a*4 + q][j] + dbv[a*4+q];
    }
  }
}

__global__ __launch_bounds__(256) void heads1x1(
    const float* __restrict__ t, const float* __restrict__ ow, const float* __restrict__ ob,
    const float* __restrict__ dw, const float* __restrict__ db,
    float* __restrict__ comb, float* __restrict__ scores, int HW, int lbase, int n) {
  heads_body(t, ow, ob, dw, db, comb, scores, HW, lbase, n,
             (blockIdx.x*256 + threadIdx.x)*4);
}

// fused heads: all levels of one image. 86 blocks.
__global__ __launch_bounds__(256) void heads_fused(
    const float* __restrict__ t, const float* __restrict__ ow, const float* __restrict__ ob,
    const float* __restrict__ dw, const float* __restrict__ db,
    float* __restrict__ comb, float* __restrict__ scores, int n) {
  int b = blockIdx.x;
  int lvl, pb;
  if (b < 64)      { lvl = 0; pb = b; }
  else if (b < 80) { lvl = 1; pb = b - 64; }
  else if (b < 84) { lvl = 2; pb = b - 80; }
  else if (b < 85) { lvl = 3; pb = 0; }
  else             { lvl = 4; pb = 0; }
  int HW = LW[lvl]*LW[lvl];
  heads_body(t + TOFF[lvl], ow, ob, dw, db, comb, scores, HW, LBASE[lvl], n,
             pb*1024 + threadIdx.x*4);
}

// ---------------- decode ----------------
__device__ void decode_store(int n, int lvl, int idx, int slot,
                             const float* comb, float* cboxes, float* cscores) {
  int W = LW[lvl];
  int a = idx % 3; int p = idx / 3;
  int wx = p % W, hy = p / W;
  double r = (a == 0) ? 0.5 : (a == 1) ? 1.0 : 2.0;
  double sz = (double)LSZ[lvl];
  double wsd = sqrt(sz*sz/r);
  double hsd = wsd * r;
  double cxd = (double)(wx * LSTR[lvl]);
  double cyd = (double)(hy * LSTR[lvl]);
  float ax1 = (float)(cxd - 0.5*wsd), ay1 = (float)(cyd - 0.5*hsd);
  float ax2 = (float)(cxd + 0.5*wsd), ay2 = (float)(cyd + 0.5*hsd);
  float aw = ax2 - ax1, ah = ay2 - ay1;
  float acx = ax1 + 0.5f*aw, acy = ay1 + 0.5f*ah;
  long g = (long)n*ATOT + LBASE[lvl] + idx;
  const float* cm = comb + g*5;
  float sc = cm[0];
  float dx = cm[1], dy = cm[2], dwv = cm[3], dhv = cm[4];
  dwv = fminf(dwv, SCALE_CLAMP); dhv = fminf(dhv, SCALE_CLAMP);
  float pcx = __fadd_rn(__fmul_rn(dx, aw), acx);
  float pcy = __fadd_rn(__fmul_rn(dy, ah), acy);
  float pw = __fmul_rn(expf(dwv), aw);
  float ph = __fmul_rn(expf(dhv), ah);
  float x1 = __fsub_rn(pcx, 0.5f*pw), y1 = __fsub_rn(pcy, 0.5f*ph);
  float x2 = __fadd_rn(pcx, 0.5f*pw), y2 = __fadd_rn(pcy, 0.5f*ph);
  x1 = fminf(fmaxf(x1, 0.f), 1024.f);
  y1 = fminf(fmaxf(y1, 0.f), 1024.f);
  x2 = fminf(fmaxf(x2, 0.f), 1024.f);
  y2 = fminf(fmaxf(y2, 0.f), 1024.f);
  float* cbp = cboxes + ((long)n*MCAND + slot)*4;
  cbp[0]=x1; cbp[1]=y1; cbp[2]=x2; cbp[3]=y2;
  cscores[(long)n*MCAND + slot] = sc;
}

// ---------------- top-k kernels ----------------
__global__ void init_ctl(unsigned* ctl) {
  for (int i = threadIdx.x; i < CTL_SIZE; i += 256) ctl[i] = 0;
  __syncthreads();
  if (threadIdx.x < 6) ctl[C_KCUR + threadIdx.x] = 6000;
  if (threadIdx.x < 2) ctl[N_THRPREV + threadIdx.x] = 0xFFFFFFFFu;
}

__global__ __launch_bounds__(256) void tk_hist(const float* __restrict__ scores,
                                               unsigned* ctl, int pass) {
  int t = blockIdx.y; int lvl = t >> 1, n = t & 1;
  int M = LM[lvl]; long base = (long)n*ATOT + LBASE[lvl];
  __shared__ unsigned h[256];
  h[threadIdx.x] = 0;
  __syncthreads();
  unsigned prefix = ctl[C_PRE + t];
  int shift = 24 - 8*pass;
  for (int i = blockIdx.x*256 + threadIdx.x; i < M; i += gridDim.x*256) {
    unsigned key = fkey(scores[base + i]);
    if (pass == 0 || (key >> (shift+8)) == prefix)
      atomicAdd(&h[(key >> shift) & 255], 1u);
  }
  __syncthreads();
  if (h[threadIdx.x]) atomicAdd(&ctl[C_GH + t*256 + threadIdx.x], h[threadIdx.x]);
}

__global__ __launch_bounds__(256) void tk_pick(unsigned* ctl) {
  int t = blockIdx.x;
  if (threadIdx.x == 0) {
    unsigned kcur = ctl[C_KCUR + t];
    int digit = 0;
    for (int d = 255; d >= 0; --d) {
      unsigned c = ctl[C_GH + t*256 + d];
      if (kcur <= c) { digit = d; break; }
      kcur -= c;
    }
    ctl[C_KCUR + t] = kcur;
    ctl[C_PRE + t] = (ctl[C_PRE + t] << 8) | (unsigned)digit;
  }
  __syncthreads();
  ctl[C_GH + t*256 + threadIdx.x] = 0;
}

__global__ __launch_bounds__(256) void tk_compact(const float* __restrict__ scores,
    const float* __restrict__ comb, unsigned* ctl, float* cboxes, float* cscores) {
  int t = blockIdx.y; int lvl = t >> 1, n = t & 1;
  int M = LM[lvl]; long base = (long)n*ATOT + LBASE[lvl];
  unsigned thr = ctl[C_PRE + t];
  for (int i = blockIdx.x*256 + threadIdx.x; i < M; i += gridDim.x*256) {
    unsigned key = fkey(scores[base + i]);
    if (key > thr) {
      unsigned p = atomicAdd(&ctl[C_CNT + t], 1u);
      if (p < 6000u) decode_store(n, lvl, i, CBASE[lvl] + (int)p, comb, cboxes, cscores);
    } else if (key == thr) {
      unsigned p = atomicAdd(&ctl[C_TIE + t], 1u);
      if (p < 1024u) ctl[C_TIEIDX + t*1024 + p] = (unsigned)i;
    }
  }
}

__global__ void tk_finalize(const float* __restrict__ comb, unsigned* ctl,
                            float* cboxes, float* cscores) {
  int t = blockIdx.x; int lvl = t >> 1, n = t & 1;
  if (threadIdx.x != 0) return;
  int cnt = (int)ctl[C_CNT + t]; if (cnt > 6000) cnt = 6000;
  int need = 6000 - cnt;
  int tc = (int)ctl[C_TIE + t]; if (tc > 1024) tc = 1024;
  unsigned* tb = &ctl[C_TIEIDX + t*1024];
  for (int s = 0; s < need; ++s) {
    unsigned mn = 0xFFFFFFFFu; int mi = -1;
    for (int q = 0; q < tc; ++q) { if (tb[q] < mn) { mn = tb[q]; mi = q; } }
    int slot = CBASE[lvl] + cnt + s;
    if (mi >= 0) {
      tb[mi] = 0xFFFFFFFFu;
      decode_store(n, lvl, (int)mn, slot, comb, cboxes, cscores);
    } else {
      float* cbp = cboxes + ((long)n*MCAND + slot)*4;
      cbp[0]=cbp[1]=cbp[2]=cbp[3]=0.f;
      cscores[(long)n*MCAND + slot] = -3.0e38f;
    }
  }
}

__global__ void decode34(const float* __restrict__ comb, float* cboxes, float* cscores) {
  int n = blockIdx.y;
  int e = blockIdx.x*256 + threadIdx.x;
  if (e >= 3840) return;
  if (e < 3072) decode_store(n, 3, e, 18000 + e, comb, cboxes, cscores);
  else          decode_store(n, 4, e - 3072, 21072 + (e - 3072), comb, cboxes, cscores);
}

// =============== NMS: matrix pipeline ===============
__global__ __launch_bounds__(1024) void nms_select(
    const float* __restrict__ cscores, const float* __restrict__ cboxes,
    float* __restrict__ wt, unsigned* ctl) {
  const int n = blockIdx.x;
  if (ctl[N_DONE + n]) return;
  const int tid = threadIdx.x;
  const float* sc = cscores + (long)n*MCAND;
  const float* cb = cboxes + (long)n*MCAND*4;
  u64* skeyG   = ((u64*)(wt + NS_KEY)) + n*RCAP;
  float* boxO  = wt + NS_BOX + n*RCAP*4;
  float* areaG = wt + NS_AREA + n*RCAP;
  __shared__ u64 skey[RCAP];
  __shared__ unsigned hist[256];
  __shared__ unsigned sS[8];
  unsigned thrPrev = ctl[N_THRPREV + n];
  unsigned prefix = 0, kcur = RCAP;
  for (int pass = 0; pass < 4; ++pass) {
    if (tid < 256) hist[tid] = 0;
    __syncthreads();
    int shift = 24 - 8*pass;
    for (int i = tid; i < MCAND; i += 1024) {
      unsigned key = fkey(sc[i]);
      if (key < thrPrev && (pass == 0 || (key >> (shift+8)) == prefix))
        atomicAdd(&hist[(key >> shift) & 255], 1u);
    }
    __syncthreads();
    if (tid == 0) {
      if (pass == 0) { unsigned s = 0; for (int d = 0; d < 256; ++d) s += hist[d]; sS[2] = s; }
      if (sS[2] > RCAP) {
        unsigned kc = kcur; int digit = 0;
        for (int d = 255; d >= 0; --d) {
          unsigned c = hist[d];
          if (kc <= c) { digit = d; break; }
          kc -= c;
        }
        kcur = kc;
        prefix = (prefix << 8) | (unsigned)digit;
        sS[4] = prefix;
      } else sS[4] = 0;
    }
    __syncthreads();
    prefix = sS[4];
    if (sS[2] <= RCAP) break;
  }
  unsigned thr = (sS[2] <= RCAP) ? 0u : sS[4];
  if (tid == 0) sS[0] = 0;
  for (int i = tid; i < RCAP; i += 1024) skey[i] = 0;
  __syncthreads();
  for (int i = tid; i < MCAND; i += 1024) {
    unsigned key = fkey(sc[i]);
    if (key < thrPrev && key >= thr) {
      unsigned p = atomicAdd(&sS[0], 1u);
      if (p < RCAP) skey[p] = ((u64)key << 32) | (unsigned)(~i);
    }
  }
  __syncthreads();
  unsigned scnt = sS[0] > RCAP ? RCAP : sS[0];
  for (int kk = 2; kk <= RCAP; kk <<= 1) {
    for (int jj = kk >> 1; jj > 0; jj >>= 1) {
      for (int i = tid; i < RCAP; i += 1024) {
        int ixj = i ^ jj;
        if (ixj > i) {
          u64 a = skey[i], b = skey[ixj];
          bool up = ((i & kk) == 0);
          if ((a < b) == up) { skey[i] = b; skey[ixj] = a; }
        }
      }
      __syncthreads();
    }
  }
  for (int s = tid; s < RCAP; s += 1024) {
    u64 v = skey[s];
    skeyG[s] = v;
    float x1=0.f,y1=0.f,x2=0.f,y2=0.f,ar=0.f;
    if (v) {
      int idx = (int)(~(unsigned)v);
      float off = 2000.f * (float)lvl_of(idx);
      x1 = cb[idx*4+0] + off; y1 = cb[idx*4+1] + off;
      x2 = cb[idx*4+2] + off; y2 = cb[idx*4+3] + off;
      ar = (x2-x1)*(y2-y1);
    }
    boxO[s*4+0]=x1; boxO[s*4+1]=y1; boxO[s*4+2]=x2; boxO[s*4+3]=y2;
    areaG[s]=ar;
  }
  if (tid == 0) {
    ctl[N_SCNT + n] = scnt;
    ctl[N_THRPREV + n] = thr;
    if (thr == 0u) ctl[N_LAST + n] = 1;
    if (scnt == 0) ctl[N_DONE + n] = 1;
  }
}

__global__ __launch_bounds__(256) void nms_matrix(const float* __restrict__ wt_c,
                                                  float* __restrict__ wt, unsigned* ctl) {
  const int n = blockIdx.y;
  if (ctl[N_DONE + n]) return;
  const int bx = blockIdx.x;
  const int i0 = bx * 64;
  const int tid = threadIdx.x;
  const int wv = tid >> 6;
  const int lane = tid & 63;
  const float* boxO  = wt_c + NS_BOX + n*RCAP*4;
  const float* areaG = wt_c + NS_AREA + n*RCAP;
  const float* kbox  = wt_c + NS_KBOX + n*1024*5;
  u64* mask  = ((u64*)(wt + NS_MASK)) + (long)n*RCAP*64;
  u64* diagA = ((u64*)(wt + NS_DIAG)) + n*64*64;
  u64* psupW = ((u64*)(wt + NS_PSUP)) + n*64;
  int kt0 = (int)ctl[N_KEPT + n];
  __shared__ float rb[64][5];
  __shared__ unsigned psw[2];
  if (tid < 2) psw[tid] = 0;
  if (tid < 64) {
    rb[tid][0]=boxO[(i0+tid)*4+0]; rb[tid][1]=boxO[(i0+tid)*4+1];
    rb[tid][2]=boxO[(i0+tid)*4+2]; rb[tid][3]=boxO[(i0+tid)*4+3];
    rb[tid][4]=areaG[i0+tid];
  }
  __syncthreads();
  if (kt0 > 0) {
    for (int rr = 0; rr < 16; ++rr) {
      int il = wv*16 + rr;
      float rx1=rb[il][0], ry1=rb[il][1], rx2=rb[il][2], ry2=rb[il][3], rar=rb[il][4];
      bool s = false;
      for (int k = lane; k < kt0; k += 64) {
        float iou = iou_f(rx1,ry1,rx2,ry2,rar,
                          kbox[k*5+0],kbox[k*5+1],kbox[k*5+2],kbox[k*5+3],kbox[k*5+4]);
        s |= (iou > 0.7f);
      }
      u64 bal = __ballot(s);
      if (lane == 0 && bal) atomicOr(&psw[il>>5], 1u << (il & 31));
    }
  }
  __syncthreads();
  if (tid == 0) psupW[bx] = ((u64)psw[1] << 32) | psw[0];
  for (int w = 0; w < 64; ++w) {
    int cidx = w*64 + lane;
    float cx1=boxO[cidx*4+0], cy1=boxO[cidx*4+1], cx2=boxO[cidx*4+2], cy2=boxO[cidx*4+3];
    float car=areaG[cidx];
    #pragma unroll 4
    for (int rr = 0; rr < 16; ++rr) {
      int il = wv*16 + rr;
      int i = i0 + il;
      float iou = iou_f(rb[il][0],rb[il][1],rb[il][2],rb[il][3],rb[il][4],
                        cx1,cy1,cx2,cy2,car);
      bool bit = (iou > 0.7f) && (cidx > i);
      u64 m = __ballot(bit);
      if (lane == 0) {
        mask[(long)i*64 + w] = m;
        if (w == bx) diagA[bx*64 + il] = m;
      }
    }
  }
}

__global__ __launch_bounds__(64) void nms_scan(
    const float* __restrict__ cscores, const float* __restrict__ cboxes,
    float* __restrict__ wt, unsigned* ctl, float* __restrict__ dout) {
  const int n = blockIdx.x;
  if (ctl[N_DONE + n]) return;
  const int lane = threadIdx.x;
  const float* cb = cboxes + (long)n*MCAND*4;
  u64* skeyG = ((u64*)(wt + NS_KEY)) + n*RCAP;
  const float* boxO  = wt + NS_BOX + n*RCAP*4;
  const float* areaG = wt + NS_AREA + n*RCAP;
  u64* mask  = ((u64*)(wt + NS_MASK)) + (long)n*RCAP*64;
  u64* diagA = ((u64*)(wt + NS_DIAG)) + n*64*64;
  u64* psupW = ((u64*)(wt + NS_PSUP)) + n*64;
  float* kbox = wt + NS_KBOX + n*1024*5;
  float* keepB = dout + KB_OFF + (long)n*4*POSTK;
  float* keepS = dout + KS_OFF + (long)n*POSTK;
  float* keepV = dout + KV_OFF + (long)n*POSTK;
  int scnt = (int)ctl[N_SCNT + n];
  int kt = (int)ctl[N_KEPT + n];
  __shared__ u64 alive[64];
  {
    int rem = scnt - lane*64;
    u64 a = rem >= 64 ? ~0ull : (rem > 0 ? ((1ull << rem) - 1ull) : 0ull);
    alive[lane] = a & ~psupW[lane];
  }
  __syncthreads();
  for (int c = 0; c < 64 && kt < POSTK; ++c) {
    u64 w64 = alive[c];
    if (!w64) continue;
    u64 diag = diagA[c*64 + lane];
    u64 kb = 0;
    while (w64) {
      int b = __ffsll(w64) - 1;
      kb |= (1ull << b);
      w64 &= ~(1ull << b);
      u64 sup = __shfl(diag, b);
      w64 &= ~sup;
      if (++kt >= POSTK) break;
    }
    alive[c] = 0;
    if ((kb >> lane) & 1) {
      int base = kt - (int)__popcll(kb);
      int pos = base + (int)__popcll(kb & ((1ull << lane) - 1ull));
      int s = c*64 + lane;
      u64 v = skeyG[s];
      int idx = (int)(~(unsigned)v);
      keepB[pos*4+0]=cb[idx*4+0]; keepB[pos*4+1]=cb[idx*4+1];
      keepB[pos*4+2]=cb[idx*4+2]; keepB[pos*4+3]=cb[idx*4+3];
      keepS[pos] = unfkey((unsigned)(v >> 32));
      keepV[pos] = 1.f;
      kbox[pos*5+0]=boxO[s*4+0]; kbox[pos*5+1]=boxO[s*4+1];
      kbox[pos*5+2]=boxO[s*4+2]; kbox[pos*5+3]=boxO[s*4+3];
      kbox[pos*5+4]=areaG[s];
    }
    __syncthreads();
    if (kb && lane > c && alive[lane]) {
      u64 acc = 0, m = kb;
      while (m) {
        int b = __ffsll(m) - 1; m &= m - 1;
        acc |= mask[(long)(c*64 + b)*64 + lane];
      }
      if (acc) alive[lane] &= ~acc;
    }
    __syncthreads();
  }
  if (lane == 0) {
    ctl[N_KEPT + n] = (unsigned)kt;
    if (kt >= POSTK || ctl[N_LAST + n]) ctl[N_DONE + n] = 1;
  }
}

__device__ inline u64 shfl_down_u64d(u64 v, int o) {
  unsigned hi = __shfl_down((unsigned)(v >> 32), o);
  unsigned lo = __shfl_down((unsigned)v, o);
  return ((u64)hi << 32) | lo;
}
__global__ __launch_bounds__(1024) void nms_fill(
    const float* __restrict__ cscores, const float* __restrict__ cboxes,
    unsigned* ctl, float* __restrict__ dout) {
  const int n = blockIdx.x;
  const int tid = threadIdx.x;
  const int lane = tid & 63;
  const int wid = tid >> 6;
  const float* sc = cscores + (long)n*MCAND;
  const float* cb = cboxes + (long)n*MCAND*4;
  float* keepB = dout + KB_OFF + (long)n*4*POSTK;
  float* keepS = dout + KS_OFF + (long)n*POSTK;
  float* keepV = dout + KV_OFF + (long)n*POSTK;
  __shared__ u64 wred[16];
  __shared__ u64 sBest;
  u64 best = 0;
  for (int i = tid; i < 6000; i += 1024) {
    u64 v = ((u64)fkey(sc[i]) << 32) | (unsigned)(~i);
    if (v > best) best = v;
  }
  for (int o = 32; o > 0; o >>= 1) {
    u64 ov = shfl_down_u64d(best, o);
    if (ov > best) best = ov;
  }
  if (lane == 0) wred[wid] = best;
  __syncthreads();
  if (tid == 0) {
    u64 b = 0;
    for (int i = 0; i < 16; ++i) if (wred[i] > b) b = wred[i];
    sBest = b;
  }
  __syncthreads();
  int kt = (int)ctl[N_KEPT + n];
  int bidx = (int)(~(unsigned)sBest);
  float b0 = cb[bidx*4+0], b1 = cb[bidx*4+1], b2 = cb[bidx*4+2], b3 = cb[bidx*4+3];
  float bsc = sc[bidx];
  for (int s2 = kt + tid; s2 < POSTK; s2 += 1024) {
    keepB[s2*4+0]=b0; keepB[s2*4+1]=b1; keepB[s2*4+2]=b2; keepB[s2*4+3]=b3;
    keepS[s2] = bsc; keepV[s2] = 0.f;
  }
}

// ---------------- launcher ----------------
extern "C" void kernel_launch(void* const* d_in, const int* in_sizes, int n_in,
                              void* d_out, int out_size, void* d_ws, size_t ws_size,
                              hipStream_t stream) {
  const float* feats[5];
  for (int i = 0; i < 5; ++i) feats[i] = (const float*)d_in[i];
  const float* conv_w  = (const float*)d_in[5];
  const float* conv_b  = (const float*)d_in[6];
  const float* obj_w   = (const float*)d_in[7];
  const float* obj_b   = (const float*)d_in[8];
  const float* delta_w = (const float*)d_in[9];
  const float* delta_b = (const float*)d_in[10];
  float* out = (float*)d_out;
  float* ws = (float*)d_ws;

  const bool big = ws_size >= (size_t)FT_END * 4ull;
  float *t, *scores, *cboxes, *cscores, *wp;
  unsigned* ctl;
  if (big) {
    t = ws + FT_T; scores = ws + FT_SC; cboxes = ws + FT_CB;
    cscores = ws + FT_CS; ctl = (unsigned*)(ws + FT_CTL); wp = ws + FT_WP;
  } else {
    t = ws + WS_T; scores = ws + WS_SC; cboxes = ws + WS_CB;
    cscores = ws + WS_CS; ctl = (unsigned*)(ws + WS_CTL); wp = ws + WS_WP;
  }

  static const int LWh[5]    = {256,128,64,32,16};
  static const int LBASEh[5] = {0,196608,245760,258048,261120};

  wprep_kernel<<<dim3(2304), dim3(256), 0, stream>>>(conv_w, wp);
  init_ctl<<<dim3(1), dim3(256), 0, stream>>>(ctl);

  if (big) {
    for (int n = 0; n < 2; ++n) {
      conv_fused<<<dim3(1364), dim3(256), 0, stream>>>(
          feats[0], feats[1], feats[2], feats[3], feats[4], wp, conv_b, t, n);
      heads_fused<<<dim3(86), dim3(256), 0, stream>>>(
          t, obj_w, obj_b, delta_w, delta_b, out, scores, n);
    }
  } else {
    for (int n = 0; n < 2; ++n) {
      for (int lvl = 0; lvl < 5; ++lvl) {
        int H = LWh[lvl], W = LWh[lvl], HW = H*W;
        conv3x3_relu<<<dim3(W/16, H/16, 4), dim3(256), 0, stream>>>(
            feats[lvl] + (long)n*256*HW, wp, conv_b, t, H, W);
        int hb = (HW + 1023) / 1024;
        heads1x1<<<dim3(hb), dim3(256), 0, stream>>>(
            t, obj_w, obj_b, delta_w, delta_b, out, scores, HW, LBASEh[lvl], n);
      }
    }
  }

  for (int p = 0; p < 4; ++p) {
    tk_hist<<<dim3(48,6), dim3(256), 0, stream>>>(scores, ctl, p);
    tk_pick<<<dim3(6), dim3(256), 0, stream>>>(ctl);
  }
  tk_compact<<<dim3(48,6), dim3(256), 0, stream>>>(scores, out, ctl, cboxes, cscores);
  tk_finalize<<<dim3(6), dim3(64), 0, stream>>>(out, ctl, cboxes, cscores);
  decode34<<<dim3(15,2), dim3(256), 0, stream>>>(out, cboxes, cscores);
  for (int b = 0; b < 6; ++b) {
    nms_select<<<dim3(2), dim3(1024), 0, stream>>>(cscores, cboxes, t, ctl);
    nms_matrix<<<dim3(64,2), dim3(256), 0, stream>>>(t, t, ctl);
    nms_scan<<<dim3(2), dim3(64), 0, stream>>>(cscores, cboxes, t, ctl, out);
  }
  nms_fill<<<dim3(2), dim3(1024), 0, stream>>>(cscores, cboxes, ctl, out);
}